// Round 9
// baseline (620.948 us; speedup 1.0000x reference)
//
#include <hip/hip_runtime.h>
#include <hip/hip_bf16.h>
#include <hip/hip_fp16.h>

// GATv2 3-layer, N=80000 E=1280000 FIN=128 H=64 OUT=10. fp32 compute.
// Round 9: exp hoisted out of agg2 (was ~half its VALU): m0_kernel computes
// per-node self-loop baseline; score_kernel stores finished softmax weight
// exp(score-m0[dst]); agg2 per-edge = s_load + 2B gather + 2 fma. No xr/att
// in agg2. Deterministic partition + fused readout retained.

#define NN 80000
#define EE 1280000
#define FIN 128
#define HH 64
#define OUTD 10
#define NBUK 79            // dst>>10 buckets (79*1024 >= 80000)
#define PCH 2048           // edges per partition chunk
#define NCH 625            // EE / PCH

typedef __hip_bfloat16 bf16;

__device__ __forceinline__ float ldw(const void* p, int i, int f) {
    return f ? __bfloat162float(((const bf16*)p)[i]) : ((const float*)p)[i];
}

// ---------------- dtype detect ----------------
__global__ void detect_kernel(const unsigned* __restrict__ w, int* __restrict__ flag) {
    int lane = threadIdx.x;
    int big = 0;
    for (int i = lane; i < 2048; i += 64) {
        unsigned u = w[i];
        float a = __uint_as_float(u << 16);
        float b = __uint_as_float(u & 0xffff0000u);
        if (!(fabsf(a) <= 1024.f)) big = 1;
        if (!(fabsf(b) <= 1024.f)) big = 1;
    }
    big = (__ballot(big) != 0ull) ? 1 : 0;
    if (lane == 0) flag[0] = big ? 0 : 1;     // 1 = bf16 storage, 0 = fp32
}

// ---------------- preconvert weights: WT[k*128 + j] ----------------
__global__ void preconvert(
    const void* Wl0, const void* Wr0, const void* Wl1, const void* Wr1,
    const void* Wl2, const void* Wr2,
    const void* bl0, const void* br0, const void* bl1, const void* br1,
    const void* bl2, const void* br2,
    const void* att0, const void* att1, const void* att2,
    const void* b0, const void* b1, const void* b2,
    const void* Wro, const void* bro,
    float* WT0, float* WT1, float* WT2, float* small,
    const int* __restrict__ flagp)
{
    const int f = flagp[0];
    int t = blockIdx.x * 256 + threadIdx.x;
    if (t < 16384) {
        int j = t & 127, k = t >> 7;
        float v = (j < 64) ? ldw(Wl0, j * 128 + k, f) : ldw(Wr0, (j - 64) * 128 + k, f);
        WT0[k * 128 + j] = v;
    } else if (t < 24576) {
        int u = t - 16384; int j = u & 127, k = u >> 7;
        float v = (j < 64) ? ldw(Wl1, j * 64 + k, f) : ldw(Wr1, (j - 64) * 64 + k, f);
        WT1[k * 128 + j] = v;
    } else if (t < 32768) {
        int u = t - 24576; int j = u & 127, k = u >> 7;
        float v = (j < 64) ? ldw(Wl2, j * 64 + k, f) : ldw(Wr2, (j - 64) * 64 + k, f);
        WT2[k * 128 + j] = v;
    } else if (t < 34304) {
        int s = t - 32768;
        const void* BL[3] = { bl0, bl1, bl2 };
        const void* BR[3] = { br0, br1, br2 };
        const void* AT[3] = { att0, att1, att2 };
        const void* BB[3] = { b0, b1, b2 };
        float v = 0.f;
        if (s < 384) {
            int l = s / 128, r = s % 128;
            v = (r < 64) ? ldw(BL[l], r, f) : ldw(BR[l], r - 64, f);
        } else if (s < 576) {
            int q = s - 384; v = ldw(AT[q / 64], q % 64, f);
        } else if (s < 768) {
            int q = s - 576; v = ldw(BB[q / 64], q % 64, f);
        } else if (s < 1408) {
            v = ldw(Wro, s - 768, f);
        } else if (s < 1418) {
            v = ldw(bro, s - 1408, f);
        } else return;
        small[s] = v;
    }
}

// ---------------- A: per-chunk bucket histogram ----------------
__global__ __launch_bounds__(256) void chunkhist_kernel(const int* __restrict__ dst,
                                                        int* __restrict__ chunkcnt)
{
    __shared__ int h[NBUK];
    const int tid = threadIdx.x, c = blockIdx.x;
    for (int i = tid; i < NBUK; i += 256) h[i] = 0;
    __syncthreads();
    const int e0 = c * PCH + tid * 8;
    int4 a = *(const int4*)(dst + e0);
    int4 b = *(const int4*)(dst + e0 + 4);
    atomicAdd(&h[a.x >> 10], 1); atomicAdd(&h[a.y >> 10], 1);
    atomicAdd(&h[a.z >> 10], 1); atomicAdd(&h[a.w >> 10], 1);
    atomicAdd(&h[b.x >> 10], 1); atomicAdd(&h[b.y >> 10], 1);
    atomicAdd(&h[b.z >> 10], 1); atomicAdd(&h[b.w >> 10], 1);
    __syncthreads();
    for (int i = tid; i < NBUK; i += 256) chunkcnt[i * NCH + c] = h[i];
}

// ---------------- B1: per-bucket exclusive scan over chunk counts ----------
__global__ __launch_bounds__(1024) void cscan_kernel(int* __restrict__ chunkcnt,
                                                     int* __restrict__ bucket_cnt)
{
    __shared__ int s[1024];
    const int b = blockIdx.x, t = threadIdx.x;
    int v = (t < NCH) ? chunkcnt[b * NCH + t] : 0;
    s[t] = v;
    __syncthreads();
    #pragma unroll
    for (int off = 1; off < 1024; off <<= 1) {
        int u = (t >= off) ? s[t - off] : 0;
        __syncthreads();
        s[t] += u;
        __syncthreads();
    }
    if (t < NCH) chunkcnt[b * NCH + t] = s[t] - v;
    if (t == NCH - 1) bucket_cnt[b] = s[t];
}

// ---------------- B2: scan buckets -> bucket_base ----------------
__global__ void bscan_kernel(const int* __restrict__ bucket_cnt,
                             int* __restrict__ bucket_base)
{
    __shared__ int sc[128];
    const int t = threadIdx.x;
    sc[t] = (t < NBUK) ? bucket_cnt[t] : 0;
    __syncthreads();
    #pragma unroll
    for (int off = 1; off < 128; off <<= 1) {
        int v = (t >= off) ? sc[t - off] : 0;
        __syncthreads();
        sc[t] += v;
        __syncthreads();
    }
    if (t < NBUK) bucket_base[t] = (t == 0) ? 0 : sc[t - 1];
    if (t == 0) bucket_base[NBUK] = sc[NBUK - 1];
}

// ---------------- C: deterministic partition into buckets -------------------
__global__ __launch_bounds__(256) void part_kernel(const int* __restrict__ src,
                                                   const int* __restrict__ dst,
                                                   const int* __restrict__ chunkcnt,
                                                   const int* __restrict__ bucket_base,
                                                   int2* __restrict__ part)
{
    __shared__ int hcnt[NBUK];
    __shared__ int sc[128];
    __shared__ int hbase[NBUK + 1];
    __shared__ int hpos[NBUK];
    __shared__ int hgb[NBUK];
    __shared__ int2 stage[PCH];
    const int tid = threadIdx.x, c = blockIdx.x;

    for (int i = tid; i < NBUK; i += 256) hcnt[i] = 0;
    __syncthreads();

    const int e0 = c * PCH + tid * 8;
    int4 sa = *(const int4*)(src + e0);
    int4 sb = *(const int4*)(src + e0 + 4);
    int4 da = *(const int4*)(dst + e0);
    int4 db = *(const int4*)(dst + e0 + 4);
    int dv[8] = { da.x, da.y, da.z, da.w, db.x, db.y, db.z, db.w };
    int sv[8] = { sa.x, sa.y, sa.z, sa.w, sb.x, sb.y, sb.z, sb.w };
    #pragma unroll
    for (int u = 0; u < 8; u++) atomicAdd(&hcnt[dv[u] >> 10], 1);
    __syncthreads();

    if (tid < 128) sc[tid] = (tid < NBUK) ? hcnt[tid] : 0;
    __syncthreads();
    #pragma unroll
    for (int off = 1; off < 128; off <<= 1) {
        int v = (tid < 128 && tid >= off) ? sc[tid - off] : 0;
        __syncthreads();
        if (tid < 128) sc[tid] += v;
        __syncthreads();
    }
    if (tid < NBUK) {
        int b = (tid == 0) ? 0 : sc[tid - 1];
        hbase[tid] = b;
        hpos[tid] = b;
        hgb[tid] = bucket_base[tid] + chunkcnt[tid * NCH + c];
    }
    if (tid == 0) hbase[NBUK] = PCH;
    __syncthreads();

    #pragma unroll
    for (int u = 0; u < 8; u++) {
        int p = atomicAdd(&hpos[dv[u] >> 10], 1);
        stage[p] = make_int2(sv[u], dv[u]);
    }
    __syncthreads();

    for (int s = tid; s < PCH; s += 256) {
        int lo = 0, hi = NBUK;
        #pragma unroll
        for (int it = 0; it < 7; it++) {
            int mid = (lo + hi) >> 1;
            if (hbase[mid] <= s) lo = mid; else hi = mid;
        }
        part[hgb[lo] + (s - hbase[lo])] = stage[s];
    }
}

// ---------------- fine hist: one block per bucket, LDS counters -------------
__global__ __launch_bounds__(256) void hist_part_kernel(const int2* __restrict__ part,
                                                        const int* __restrict__ bucket_base,
                                                        int* __restrict__ cnt)
{
    __shared__ int lcnt[1024];
    const int b = blockIdx.x, tid = threadIdx.x;
    const int dbase = b << 10;
    for (int i = tid; i < 1024; i += 256) lcnt[i] = 0;
    __syncthreads();
    const int eb = bucket_base[b], ee = bucket_base[b + 1];
    for (int e = eb + tid; e < ee; e += 256)
        atomicAdd(&lcnt[part[e].y - dbase], 1);
    __syncthreads();
    const int nd = min(1024, NN - dbase);
    for (int i = tid; i < nd; i += 256) cnt[dbase + i] = lcnt[i];
}

// ---------------- scans ----------------
__global__ void scan1(const int* __restrict__ cnt, int* __restrict__ rowptr,
                      int* __restrict__ bsums) {
    __shared__ int sh[256];
    int i = blockIdx.x * 256 + threadIdx.x;
    int tid = threadIdx.x;
    int c = (i < NN) ? cnt[i] : 0;
    sh[tid] = c;
    __syncthreads();
    #pragma unroll
    for (int off = 1; off < 256; off <<= 1) {
        int t = (tid >= off) ? sh[tid - off] : 0;
        __syncthreads();
        sh[tid] += t;
        __syncthreads();
    }
    if (i < NN) rowptr[i + 1] = sh[tid];
    if (tid == 255) bsums[blockIdx.x] = sh[255];
}

__global__ void scan2(int* __restrict__ bsums, int nb) {
    __shared__ int sh[512];
    int t = threadIdx.x;
    sh[t] = (t < nb) ? bsums[t] : 0;
    __syncthreads();
    #pragma unroll
    for (int off = 1; off < 512; off <<= 1) {
        int v = (t >= off) ? sh[t - off] : 0;
        __syncthreads();
        sh[t] += v;
        __syncthreads();
    }
    if (t < nb) bsums[t] = sh[t];
}

__global__ void scan3(int* __restrict__ rowptr, const int* __restrict__ bsums) {
    int i = blockIdx.x * 256 + threadIdx.x;
    if (i == 0) rowptr[0] = 0;
    int add = (blockIdx.x == 0) ? 0 : bsums[blockIdx.x - 1];
    if (i < NN) rowptr[i + 1] += add;
}

// ---------------- P2: fine scatter, one block per bucket --------------------
__global__ __launch_bounds__(256) void scatter2_kernel(const int2* __restrict__ part,
                                                       const int* __restrict__ bucket_base,
                                                       const int* __restrict__ rowptr,
                                                       int2* __restrict__ col2)
{
    __shared__ int lfill[1024];
    const int b = blockIdx.x, tid = threadIdx.x;
    const int dbase = b << 10;
    const int nd = min(1024, NN - dbase);
    for (int i = tid; i < nd; i += 256) lfill[i] = rowptr[dbase + i];
    __syncthreads();
    const int eb = bucket_base[b], ee = bucket_base[b + 1];
    for (int e = eb + tid; e < ee; e += 256) {
        int2 sd = part[e];
        int pos = atomicAdd(&lfill[sd.y - dbase], 1);
        col2[pos] = sd;
    }
}

// ---------------- linear: xl (fp16) | xr (fp32) ----------------
template<int F, bool L0>
__global__ __launch_bounds__(256) void lin_fast(const void* __restrict__ hin_,
                                                const float* __restrict__ WT,
                                                const float* __restrict__ biasLR,
                                                __half* __restrict__ xlh,
                                                float* __restrict__ xr,
                                                const int* __restrict__ flagp)
{
    constexpr int LDR = 72;
    __shared__ __align__(16) float xs[F * LDR];
    const int t = threadIdx.x;
    const int nb = blockIdx.x * 64;

    if (L0 && flagp[0]) {
        const unsigned* hp = (const unsigned*)hin_;
        for (int idx = t; idx < 64 * (F / 2); idx += 256) {
            int r = idx / (F / 2), c = idx % (F / 2);
            unsigned u = hp[(size_t)(nb + r) * (F / 2) + c];
            xs[(2 * c) * LDR + r]     = __uint_as_float(u << 16);
            xs[(2 * c + 1) * LDR + r] = __uint_as_float(u & 0xffff0000u);
        }
    } else {
        const float* hp = (const float*)hin_;
        for (int idx = t; idx < 64 * F; idx += 256) {
            int r = idx / F, c = idx % F;
            xs[c * LDR + r] = hp[(size_t)(nb + r) * F + c];
        }
    }
    __syncthreads();

    const int c = t & 31;
    const int g = t >> 5;
    const float4* W4 = (const float4*)WT;
    const float4 bias = ((const float4*)biasLR)[c];
    float4 acc[8];
    #pragma unroll
    for (int u = 0; u < 8; u++) acc[u] = bias;

    #pragma unroll 2
    for (int k = 0; k < F; k++) {
        float4 w  = W4[k * 32 + c];
        float4 xa = *(const float4*)&xs[k * LDR + g * 8];
        float4 xb = *(const float4*)&xs[k * LDR + g * 8 + 4];
        acc[0].x = fmaf(xa.x, w.x, acc[0].x); acc[0].y = fmaf(xa.x, w.y, acc[0].y);
        acc[0].z = fmaf(xa.x, w.z, acc[0].z); acc[0].w = fmaf(xa.x, w.w, acc[0].w);
        acc[1].x = fmaf(xa.y, w.x, acc[1].x); acc[1].y = fmaf(xa.y, w.y, acc[1].y);
        acc[1].z = fmaf(xa.y, w.z, acc[1].z); acc[1].w = fmaf(xa.y, w.w, acc[1].w);
        acc[2].x = fmaf(xa.z, w.x, acc[2].x); acc[2].y = fmaf(xa.z, w.y, acc[2].y);
        acc[2].z = fmaf(xa.z, w.z, acc[2].z); acc[2].w = fmaf(xa.z, w.w, acc[2].w);
        acc[3].x = fmaf(xa.w, w.x, acc[3].x); acc[3].y = fmaf(xa.w, w.y, acc[3].y);
        acc[3].z = fmaf(xa.w, w.z, acc[3].z); acc[3].w = fmaf(xa.w, w.w, acc[3].w);
        acc[4].x = fmaf(xb.x, w.x, acc[4].x); acc[4].y = fmaf(xb.x, w.y, acc[4].y);
        acc[4].z = fmaf(xb.x, w.z, acc[4].z); acc[4].w = fmaf(xb.x, w.w, acc[4].w);
        acc[5].x = fmaf(xb.y, w.x, acc[5].x); acc[5].y = fmaf(xb.y, w.y, acc[5].y);
        acc[5].z = fmaf(xb.y, w.z, acc[5].z); acc[5].w = fmaf(xb.y, w.w, acc[5].w);
        acc[6].x = fmaf(xb.z, w.x, acc[6].x); acc[6].y = fmaf(xb.z, w.y, acc[6].y);
        acc[6].z = fmaf(xb.z, w.z, acc[6].z); acc[6].w = fmaf(xb.z, w.w, acc[6].w);
        acc[7].x = fmaf(xb.w, w.x, acc[7].x); acc[7].y = fmaf(xb.w, w.y, acc[7].y);
        acc[7].z = fmaf(xb.w, w.z, acc[7].z); acc[7].w = fmaf(xb.w, w.w, acc[7].w);
    }

    const int j0 = 4 * c;
    if (j0 < 64) {
        #pragma unroll
        for (int u = 0; u < 8; u++) {
            size_t row = nb + g * 8 + u;
            __half* xp = xlh + row * 64 + j0;
            *(__half2*)(xp)     = __floats2half2_rn(acc[u].x, acc[u].y);
            *(__half2*)(xp + 2) = __floats2half2_rn(acc[u].z, acc[u].w);
        }
    } else {
        #pragma unroll
        for (int u = 0; u < 8; u++) {
            size_t row = nb + g * 8 + u;
            *(float4*)(xr + row * 64 + (j0 - 64)) = acc[u];
        }
    }
}

// ---------------- per-node self-loop baseline m0 ----------------
__global__ __launch_bounds__(256) void m0_kernel(const __half* __restrict__ xlh,
                                                 const float* __restrict__ xr,
                                                 const float* __restrict__ attf,
                                                 float* __restrict__ m0)
{
    int i = blockIdx.x * 256 + threadIdx.x;
    if (i >= NN) return;
    const uint4* xlp = (const uint4*)(xlh + (size_t)i * 64);
    const float4* xrp = (const float4*)(xr + (size_t)i * 64);
    const float4* at4 = (const float4*)attf;
    float acc = 0.f;
    #pragma unroll 2
    for (int c = 0; c < 8; c++) {
        uint4 u = xlp[c];
        float2 f0 = __half22float2(*(__half2*)&u.x);
        float2 f1 = __half22float2(*(__half2*)&u.y);
        float2 f2 = __half22float2(*(__half2*)&u.z);
        float2 f3 = __half22float2(*(__half2*)&u.w);
        float4 ra = xrp[2 * c], rb = xrp[2 * c + 1];
        float4 aa = at4[2 * c], ab = at4[2 * c + 1];
        float u0 = f0.x + ra.x, u1 = f0.y + ra.y, u2 = f1.x + ra.z, u3 = f1.y + ra.w;
        float u4 = f2.x + rb.x, u5 = f2.y + rb.y, u6 = f3.x + rb.z, u7 = f3.y + rb.w;
        acc = fmaf(aa.x, fmaf(0.4f, fabsf(u0), 0.6f * u0), acc);
        acc = fmaf(aa.y, fmaf(0.4f, fabsf(u1), 0.6f * u1), acc);
        acc = fmaf(aa.z, fmaf(0.4f, fabsf(u2), 0.6f * u2), acc);
        acc = fmaf(aa.w, fmaf(0.4f, fabsf(u3), 0.6f * u3), acc);
        acc = fmaf(ab.x, fmaf(0.4f, fabsf(u4), 0.6f * u4), acc);
        acc = fmaf(ab.y, fmaf(0.4f, fabsf(u5), 0.6f * u5), acc);
        acc = fmaf(ab.z, fmaf(0.4f, fabsf(u6), 0.6f * u6), acc);
        acc = fmaf(ab.w, fmaf(0.4f, fabsf(u7), 0.6f * u7), acc);
    }
    m0[i] = acc;
}

// ---------------- score: per-edge finished softmax weight ----------
__global__ __launch_bounds__(256) void score_kernel(const __half* __restrict__ xlh,
                                                    const float* __restrict__ xr,
                                                    const float* __restrict__ attf,
                                                    const float* __restrict__ m0,
                                                    const int2* __restrict__ col2,
                                                    int2* __restrict__ sq)
{
    int j = blockIdx.x * 256 + threadIdx.x;
    if (j >= EE) return;
    int2 sd = col2[j];
    const uint4* xlp = (const uint4*)(xlh + (size_t)sd.x * 64);
    const float4* xrp = (const float4*)(xr + (size_t)sd.y * 64);
    const float4* at4 = (const float4*)attf;
    float acc = 0.f;
    #pragma unroll 2
    for (int c = 0; c < 8; c++) {
        uint4 u = xlp[c];
        float2 f0 = __half22float2(*(__half2*)&u.x);
        float2 f1 = __half22float2(*(__half2*)&u.y);
        float2 f2 = __half22float2(*(__half2*)&u.z);
        float2 f3 = __half22float2(*(__half2*)&u.w);
        float4 ra = xrp[2 * c], rb = xrp[2 * c + 1];
        float4 aa = at4[2 * c], ab = at4[2 * c + 1];
        float u0 = f0.x + ra.x, u1 = f0.y + ra.y, u2 = f1.x + ra.z, u3 = f1.y + ra.w;
        float u4 = f2.x + rb.x, u5 = f2.y + rb.y, u6 = f3.x + rb.z, u7 = f3.y + rb.w;
        acc = fmaf(aa.x, fmaf(0.4f, fabsf(u0), 0.6f * u0), acc);
        acc = fmaf(aa.y, fmaf(0.4f, fabsf(u1), 0.6f * u1), acc);
        acc = fmaf(aa.z, fmaf(0.4f, fabsf(u2), 0.6f * u2), acc);
        acc = fmaf(aa.w, fmaf(0.4f, fabsf(u3), 0.6f * u3), acc);
        acc = fmaf(ab.x, fmaf(0.4f, fabsf(u4), 0.6f * u4), acc);
        acc = fmaf(ab.y, fmaf(0.4f, fabsf(u5), 0.6f * u5), acc);
        acc = fmaf(ab.z, fmaf(0.4f, fabsf(u6), 0.6f * u6), acc);
        acc = fmaf(ab.w, fmaf(0.4f, fabsf(u7), 0.6f * u7), acc);
    }
    float w = __expf(fminf(acc - m0[sd.y], 80.f));
    sq[j] = make_int2(sd.x, __float_as_int(w));
}

// ---------------- aggregation: per-node wave, precomputed weights ----------
template<bool FINAL>
__global__ __launch_bounds__(256) void agg2_kernel(const __half* __restrict__ xlh,
                                                   const float* __restrict__ bf,
                                                   const int* __restrict__ rowptr,
                                                   const int2* __restrict__ sq,
                                                   float* __restrict__ hout,
                                                   const float* __restrict__ WROf,
                                                   const float* __restrict__ brof,
                                                   void* __restrict__ out,
                                                   const int* __restrict__ flagp)
{
    const int lane = threadIdx.x & 63;
    int iw = blockIdx.x * 4 + (threadIdx.x >> 6);
    if (iw >= NN) return;
    const int i = __builtin_amdgcn_readfirstlane(iw);

    const float xli = __half2float(xlh[(size_t)i * 64 + lane]);
    float denom = 1.f;       // self loop: exp(m0 - m0) = 1
    float acc = xli;

    const int e0 = rowptr[i], e1 = rowptr[i + 1];
    const int n = e1 - e0;
    const int eL = e1 - 1;

    for (int base = 0; base < n; base += 16) {
        const int j = e0 + base;
        int2 q[16];
        #pragma unroll
        for (int u = 0; u < 16; u++) q[u] = sq[min(j + u, eL)];
        float v[16];
        #pragma unroll
        for (int u = 0; u < 16; u++) v[u] = __half2float(xlh[(size_t)q[u].x * 64 + lane]);
        float w[16];
        #pragma unroll
        for (int u = 0; u < 16; u++)
            w[u] = (base + u < n) ? __int_as_float(q[u].y) : 0.f;

        float d01 = 0.f, d23 = 0.f;
        float a01 = 0.f, a23 = 0.f;
        #pragma unroll
        for (int u = 0; u < 8; u++) {
            d01 += w[u]; d23 += w[u + 8];
            a01 = fmaf(w[u], v[u], a01);
            a23 = fmaf(w[u + 8], v[u + 8], a23);
        }
        denom += d01 + d23;
        acc += a01 + a23;
    }

    float o = fmaxf(acc / denom + bf[lane], 0.f);

    if (!FINAL) {
        hout[(size_t)i * 64 + lane] = o;
    } else {
        const int f = flagp[0];
        float res = 0.f;
        #pragma unroll
        for (int jo = 0; jo < OUTD; jo++) {
            float pr = o * WROf[jo * 64 + lane];
            #pragma unroll
            for (int off = 1; off < 64; off <<= 1) pr += __shfl_xor(pr, off, 64);
            if (lane == jo) res = pr + brof[jo];
        }
        if (lane < OUTD) {
            if (f) ((bf16*)out)[(size_t)i * OUTD + lane] = __float2bfloat16(res);
            else   ((float*)out)[(size_t)i * OUTD + lane] = res;
        }
    }
}

extern "C" void kernel_launch(void* const* d_in, const int* in_sizes, int n_in,
                              void* d_out, int out_size, void* d_ws, size_t ws_size,
                              hipStream_t stream) {
    const void* x   = d_in[0];
    const int* ei   = (const int*)d_in[1];
    const void* Wl0 = d_in[3];  const void* bl0 = d_in[4];
    const void* Wr0 = d_in[5];  const void* br0 = d_in[6];
    const void* at0 = d_in[7];  const void* b0  = d_in[8];
    const void* Wl1 = d_in[9];  const void* bl1 = d_in[10];
    const void* Wr1 = d_in[11]; const void* br1 = d_in[12];
    const void* at1 = d_in[13]; const void* b1  = d_in[14];
    const void* Wl2 = d_in[15]; const void* bl2 = d_in[16];
    const void* Wr2 = d_in[17]; const void* br2 = d_in[18];
    const void* at2 = d_in[19]; const void* b2  = d_in[20];
    const void* Wro = d_in[21]; const void* bro = d_in[22];

    const int* srcArr = ei;
    const int* dstArr = ei + EE;

    float* wf = (float*)d_ws;
    float* WT0   = wf;                        // 16384
    float* WT1   = wf + 16384;                // 8192
    float* WT2   = wf + 24576;                // 8192
    float* small = wf + 32768;                // 1536
    int*   flag  = (int*)(wf + 34304);        // pad 64
    int*   rowptr = (int*)(wf + 34368);       // 80001 (pad 80128)
    int*   bsums  = (int*)(wf + 114496);      // 512
    int*   fillc  = (int*)(wf + 115008);      // 80000 (CSR phase only)
    float* m0v    = (float*)fillc;            // alias: m0 used in layer phase,
                                              // fillc dead after scan1
    int*   bucket_cnt  = (int*)(wf + 195008); // 128
    int*   bucket_base = (int*)(wf + 195136); // 128 (+1 used)
    int*   chunkcnt    = (int*)(wf + 195264); // NBUK*NCH = 49375 (pad 49472)
    int2*  part   = (int2*)(wf + 244736);     // EE int2 = 2560000 ints
    int2*  col2   = (int2*)(wf + 2804736);    // 2560000
    int2*  sq     = (int2*)(wf + 5364736);    // 2560000
    __half* xlh   = (__half*)(wf + 7924736);  // NN*64 halves = 2560000 ints
    float* xr = wf + 10484736;                // 5120000
    float* hA = xr + (size_t)NN * 64;         // 5120000

    float* biasLR0 = small;        float* biasLR1 = small + 128; float* biasLR2 = small + 256;
    float* attf0 = small + 384;    float* attf1 = small + 448;   float* attf2 = small + 512;
    float* bf0   = small + 576;    float* bf1   = small + 640;   float* bf2   = small + 704;
    float* WROf  = small + 768;    float* brof  = small + 1408;

    detect_kernel<<<dim3(1), dim3(64), 0, stream>>>((const unsigned*)Wl0, flag);

    preconvert<<<dim3(134), dim3(256), 0, stream>>>(
        Wl0, Wr0, Wl1, Wr1, Wl2, Wr2, bl0, br0, bl1, br1, bl2, br2,
        at0, at1, at2, b0, b1, b2, Wro, bro, WT0, WT1, WT2, small, flag);

    // deterministic edge sort
    chunkhist_kernel<<<dim3(NCH), dim3(256), 0, stream>>>(dstArr, chunkcnt);
    cscan_kernel<<<dim3(NBUK), dim3(1024), 0, stream>>>(chunkcnt, bucket_cnt);
    bscan_kernel<<<dim3(1), dim3(128), 0, stream>>>(bucket_cnt, bucket_base);
    part_kernel<<<dim3(NCH), dim3(256), 0, stream>>>(srcArr, dstArr, chunkcnt, bucket_base, part);
    hist_part_kernel<<<dim3(NBUK), dim3(256), 0, stream>>>(part, bucket_base, fillc);
    scan1<<<dim3(313), dim3(256), 0, stream>>>(fillc, rowptr, bsums);
    scan2<<<dim3(1), dim3(512), 0, stream>>>(bsums, 313);
    scan3<<<dim3(313), dim3(256), 0, stream>>>(rowptr, bsums);
    scatter2_kernel<<<dim3(NBUK), dim3(256), 0, stream>>>(part, bucket_base, rowptr, col2);

    // layer 0
    lin_fast<128, true><<<dim3(NN / 64), dim3(256), 0, stream>>>(x, WT0, biasLR0, xlh, xr, flag);
    m0_kernel<<<dim3(313), dim3(256), 0, stream>>>(xlh, xr, attf0, m0v);
    score_kernel<<<dim3(EE / 256), dim3(256), 0, stream>>>(xlh, xr, attf0, m0v, col2, sq);
    agg2_kernel<false><<<dim3(NN / 4), dim3(256), 0, stream>>>(xlh, bf0, rowptr, sq, hA,
                                                               WROf, brof, d_out, flag);
    // layer 1
    lin_fast<64, false><<<dim3(NN / 64), dim3(256), 0, stream>>>(hA, WT1, biasLR1, xlh, xr, flag);
    m0_kernel<<<dim3(313), dim3(256), 0, stream>>>(xlh, xr, attf1, m0v);
    score_kernel<<<dim3(EE / 256), dim3(256), 0, stream>>>(xlh, xr, attf1, m0v, col2, sq);
    agg2_kernel<false><<<dim3(NN / 4), dim3(256), 0, stream>>>(xlh, bf1, rowptr, sq, hA,
                                                               WROf, brof, d_out, flag);
    // layer 2
    lin_fast<64, false><<<dim3(NN / 64), dim3(256), 0, stream>>>(hA, WT2, biasLR2, xlh, xr, flag);
    m0_kernel<<<dim3(313), dim3(256), 0, stream>>>(xlh, xr, attf2, m0v);
    score_kernel<<<dim3(EE / 256), dim3(256), 0, stream>>>(xlh, xr, attf2, m0v, col2, sq);
    agg2_kernel<true><<<dim3(NN / 4), dim3(256), 0, stream>>>(xlh, bf2, rowptr, sq, hA,
                                                              WROf, brof, d_out, flag);
}

// Round 10
// 589.712 us; speedup vs baseline: 1.0530x; 1.0530x over previous
//
#include <hip/hip_runtime.h>
#include <hip/hip_bf16.h>
#include <hip/hip_fp16.h>

// GATv2 3-layer, N=80000 E=1280000 FIN=128 H=64 OUT=10. fp32 compute.
// Round 10: agg2 address-rate fix: one uint4 gather = 8 edges' full fp16 rows
// (lane l: subgroup g=l>>3 picks edge, octet r=l&7 picks 8 features), 27
// shuffle-adds per node to reduce subgroups. m0 dropped (shift-invariant
// softmax, clamp 60): score kernel appends self-edge weights at sq[EE+i].
// Readout back to standalone butterfly kernel.

#define NN 80000
#define EE 1280000
#define ETOT (EE + NN)
#define FIN 128
#define HH 64
#define OUTD 10
#define NBUK 79            // dst>>10 buckets (79*1024 >= 80000)
#define PCH 2048           // edges per partition chunk
#define NCH 625            // EE / PCH

typedef __hip_bfloat16 bf16;

__device__ __forceinline__ float ldw(const void* p, int i, int f) {
    return f ? __bfloat162float(((const bf16*)p)[i]) : ((const float*)p)[i];
}

// ---------------- dtype detect ----------------
__global__ void detect_kernel(const unsigned* __restrict__ w, int* __restrict__ flag) {
    int lane = threadIdx.x;
    int big = 0;
    for (int i = lane; i < 2048; i += 64) {
        unsigned u = w[i];
        float a = __uint_as_float(u << 16);
        float b = __uint_as_float(u & 0xffff0000u);
        if (!(fabsf(a) <= 1024.f)) big = 1;
        if (!(fabsf(b) <= 1024.f)) big = 1;
    }
    big = (__ballot(big) != 0ull) ? 1 : 0;
    if (lane == 0) flag[0] = big ? 0 : 1;     // 1 = bf16 storage, 0 = fp32
}

// ---------------- preconvert weights: WT[k*128 + j] ----------------
__global__ void preconvert(
    const void* Wl0, const void* Wr0, const void* Wl1, const void* Wr1,
    const void* Wl2, const void* Wr2,
    const void* bl0, const void* br0, const void* bl1, const void* br1,
    const void* bl2, const void* br2,
    const void* att0, const void* att1, const void* att2,
    const void* b0, const void* b1, const void* b2,
    const void* Wro, const void* bro,
    float* WT0, float* WT1, float* WT2, float* small,
    const int* __restrict__ flagp)
{
    const int f = flagp[0];
    int t = blockIdx.x * 256 + threadIdx.x;
    if (t < 16384) {
        int j = t & 127, k = t >> 7;
        float v = (j < 64) ? ldw(Wl0, j * 128 + k, f) : ldw(Wr0, (j - 64) * 128 + k, f);
        WT0[k * 128 + j] = v;
    } else if (t < 24576) {
        int u = t - 16384; int j = u & 127, k = u >> 7;
        float v = (j < 64) ? ldw(Wl1, j * 64 + k, f) : ldw(Wr1, (j - 64) * 64 + k, f);
        WT1[k * 128 + j] = v;
    } else if (t < 32768) {
        int u = t - 24576; int j = u & 127, k = u >> 7;
        float v = (j < 64) ? ldw(Wl2, j * 64 + k, f) : ldw(Wr2, (j - 64) * 64 + k, f);
        WT2[k * 128 + j] = v;
    } else if (t < 34304) {
        int s = t - 32768;
        const void* BL[3] = { bl0, bl1, bl2 };
        const void* BR[3] = { br0, br1, br2 };
        const void* AT[3] = { att0, att1, att2 };
        const void* BB[3] = { b0, b1, b2 };
        float v = 0.f;
        if (s < 384) {
            int l = s / 128, r = s % 128;
            v = (r < 64) ? ldw(BL[l], r, f) : ldw(BR[l], r - 64, f);
        } else if (s < 576) {
            int q = s - 384; v = ldw(AT[q / 64], q % 64, f);
        } else if (s < 768) {
            int q = s - 576; v = ldw(BB[q / 64], q % 64, f);
        } else if (s < 1408) {
            v = ldw(Wro, s - 768, f);
        } else if (s < 1418) {
            v = ldw(bro, s - 1408, f);
        } else return;
        small[s] = v;
    }
}

// ---------------- A: per-chunk bucket histogram ----------------
__global__ __launch_bounds__(256) void chunkhist_kernel(const int* __restrict__ dst,
                                                        int* __restrict__ chunkcnt)
{
    __shared__ int h[NBUK];
    const int tid = threadIdx.x, c = blockIdx.x;
    for (int i = tid; i < NBUK; i += 256) h[i] = 0;
    __syncthreads();
    const int e0 = c * PCH + tid * 8;
    int4 a = *(const int4*)(dst + e0);
    int4 b = *(const int4*)(dst + e0 + 4);
    atomicAdd(&h[a.x >> 10], 1); atomicAdd(&h[a.y >> 10], 1);
    atomicAdd(&h[a.z >> 10], 1); atomicAdd(&h[a.w >> 10], 1);
    atomicAdd(&h[b.x >> 10], 1); atomicAdd(&h[b.y >> 10], 1);
    atomicAdd(&h[b.z >> 10], 1); atomicAdd(&h[b.w >> 10], 1);
    __syncthreads();
    for (int i = tid; i < NBUK; i += 256) chunkcnt[i * NCH + c] = h[i];
}

// ---------------- B1: per-bucket exclusive scan over chunk counts ----------
__global__ __launch_bounds__(1024) void cscan_kernel(int* __restrict__ chunkcnt,
                                                     int* __restrict__ bucket_cnt)
{
    __shared__ int s[1024];
    const int b = blockIdx.x, t = threadIdx.x;
    int v = (t < NCH) ? chunkcnt[b * NCH + t] : 0;
    s[t] = v;
    __syncthreads();
    #pragma unroll
    for (int off = 1; off < 1024; off <<= 1) {
        int u = (t >= off) ? s[t - off] : 0;
        __syncthreads();
        s[t] += u;
        __syncthreads();
    }
    if (t < NCH) chunkcnt[b * NCH + t] = s[t] - v;
    if (t == NCH - 1) bucket_cnt[b] = s[t];
}

// ---------------- B2: scan buckets -> bucket_base ----------------
__global__ void bscan_kernel(const int* __restrict__ bucket_cnt,
                             int* __restrict__ bucket_base)
{
    __shared__ int sc[128];
    const int t = threadIdx.x;
    sc[t] = (t < NBUK) ? bucket_cnt[t] : 0;
    __syncthreads();
    #pragma unroll
    for (int off = 1; off < 128; off <<= 1) {
        int v = (t >= off) ? sc[t - off] : 0;
        __syncthreads();
        sc[t] += v;
        __syncthreads();
    }
    if (t < NBUK) bucket_base[t] = (t == 0) ? 0 : sc[t - 1];
    if (t == 0) bucket_base[NBUK] = sc[NBUK - 1];
}

// ---------------- C: deterministic partition into buckets -------------------
__global__ __launch_bounds__(256) void part_kernel(const int* __restrict__ src,
                                                   const int* __restrict__ dst,
                                                   const int* __restrict__ chunkcnt,
                                                   const int* __restrict__ bucket_base,
                                                   int2* __restrict__ part)
{
    __shared__ int hcnt[NBUK];
    __shared__ int sc[128];
    __shared__ int hbase[NBUK + 1];
    __shared__ int hpos[NBUK];
    __shared__ int hgb[NBUK];
    __shared__ int2 stage[PCH];
    const int tid = threadIdx.x, c = blockIdx.x;

    for (int i = tid; i < NBUK; i += 256) hcnt[i] = 0;
    __syncthreads();

    const int e0 = c * PCH + tid * 8;
    int4 sa = *(const int4*)(src + e0);
    int4 sb = *(const int4*)(src + e0 + 4);
    int4 da = *(const int4*)(dst + e0);
    int4 db = *(const int4*)(dst + e0 + 4);
    int dv[8] = { da.x, da.y, da.z, da.w, db.x, db.y, db.z, db.w };
    int sv[8] = { sa.x, sa.y, sa.z, sa.w, sb.x, sb.y, sb.z, sb.w };
    #pragma unroll
    for (int u = 0; u < 8; u++) atomicAdd(&hcnt[dv[u] >> 10], 1);
    __syncthreads();

    if (tid < 128) sc[tid] = (tid < NBUK) ? hcnt[tid] : 0;
    __syncthreads();
    #pragma unroll
    for (int off = 1; off < 128; off <<= 1) {
        int v = (tid < 128 && tid >= off) ? sc[tid - off] : 0;
        __syncthreads();
        if (tid < 128) sc[tid] += v;
        __syncthreads();
    }
    if (tid < NBUK) {
        int b = (tid == 0) ? 0 : sc[tid - 1];
        hbase[tid] = b;
        hpos[tid] = b;
        hgb[tid] = bucket_base[tid] + chunkcnt[tid * NCH + c];
    }
    if (tid == 0) hbase[NBUK] = PCH;
    __syncthreads();

    #pragma unroll
    for (int u = 0; u < 8; u++) {
        int p = atomicAdd(&hpos[dv[u] >> 10], 1);
        stage[p] = make_int2(sv[u], dv[u]);
    }
    __syncthreads();

    for (int s = tid; s < PCH; s += 256) {
        int lo = 0, hi = NBUK;
        #pragma unroll
        for (int it = 0; it < 7; it++) {
            int mid = (lo + hi) >> 1;
            if (hbase[mid] <= s) lo = mid; else hi = mid;
        }
        part[hgb[lo] + (s - hbase[lo])] = stage[s];
    }
}

// ---------------- fine hist: one block per bucket, LDS counters -------------
__global__ __launch_bounds__(256) void hist_part_kernel(const int2* __restrict__ part,
                                                        const int* __restrict__ bucket_base,
                                                        int* __restrict__ cnt)
{
    __shared__ int lcnt[1024];
    const int b = blockIdx.x, tid = threadIdx.x;
    const int dbase = b << 10;
    for (int i = tid; i < 1024; i += 256) lcnt[i] = 0;
    __syncthreads();
    const int eb = bucket_base[b], ee = bucket_base[b + 1];
    for (int e = eb + tid; e < ee; e += 256)
        atomicAdd(&lcnt[part[e].y - dbase], 1);
    __syncthreads();
    const int nd = min(1024, NN - dbase);
    for (int i = tid; i < nd; i += 256) cnt[dbase + i] = lcnt[i];
}

// ---------------- scans ----------------
__global__ void scan1(const int* __restrict__ cnt, int* __restrict__ rowptr,
                      int* __restrict__ bsums) {
    __shared__ int sh[256];
    int i = blockIdx.x * 256 + threadIdx.x;
    int tid = threadIdx.x;
    int c = (i < NN) ? cnt[i] : 0;
    sh[tid] = c;
    __syncthreads();
    #pragma unroll
    for (int off = 1; off < 256; off <<= 1) {
        int t = (tid >= off) ? sh[tid - off] : 0;
        __syncthreads();
        sh[tid] += t;
        __syncthreads();
    }
    if (i < NN) rowptr[i + 1] = sh[tid];
    if (tid == 255) bsums[blockIdx.x] = sh[255];
}

__global__ void scan2(int* __restrict__ bsums, int nb) {
    __shared__ int sh[512];
    int t = threadIdx.x;
    sh[t] = (t < nb) ? bsums[t] : 0;
    __syncthreads();
    #pragma unroll
    for (int off = 1; off < 512; off <<= 1) {
        int v = (t >= off) ? sh[t - off] : 0;
        __syncthreads();
        sh[t] += v;
        __syncthreads();
    }
    if (t < nb) bsums[t] = sh[t];
}

__global__ void scan3(int* __restrict__ rowptr, const int* __restrict__ bsums) {
    int i = blockIdx.x * 256 + threadIdx.x;
    if (i == 0) rowptr[0] = 0;
    int add = (blockIdx.x == 0) ? 0 : bsums[blockIdx.x - 1];
    if (i < NN) rowptr[i + 1] += add;
}

// ---------------- P2: fine scatter, one block per bucket --------------------
__global__ __launch_bounds__(256) void scatter2_kernel(const int2* __restrict__ part,
                                                       const int* __restrict__ bucket_base,
                                                       const int* __restrict__ rowptr,
                                                       int2* __restrict__ col2)
{
    __shared__ int lfill[1024];
    const int b = blockIdx.x, tid = threadIdx.x;
    const int dbase = b << 10;
    const int nd = min(1024, NN - dbase);
    for (int i = tid; i < nd; i += 256) lfill[i] = rowptr[dbase + i];
    __syncthreads();
    const int eb = bucket_base[b], ee = bucket_base[b + 1];
    for (int e = eb + tid; e < ee; e += 256) {
        int2 sd = part[e];
        int pos = atomicAdd(&lfill[sd.y - dbase], 1);
        col2[pos] = sd;
    }
}

// ---------------- linear: xl (fp16) | xr (fp32) ----------------
template<int F, bool L0>
__global__ __launch_bounds__(256) void lin_fast(const void* __restrict__ hin_,
                                                const float* __restrict__ WT,
                                                const float* __restrict__ biasLR,
                                                __half* __restrict__ xlh,
                                                float* __restrict__ xr,
                                                const int* __restrict__ flagp)
{
    constexpr int LDR = 72;
    __shared__ __align__(16) float xs[F * LDR];
    const int t = threadIdx.x;
    const int nb = blockIdx.x * 64;

    if (L0 && flagp[0]) {
        const unsigned* hp = (const unsigned*)hin_;
        for (int idx = t; idx < 64 * (F / 2); idx += 256) {
            int r = idx / (F / 2), c = idx % (F / 2);
            unsigned u = hp[(size_t)(nb + r) * (F / 2) + c];
            xs[(2 * c) * LDR + r]     = __uint_as_float(u << 16);
            xs[(2 * c + 1) * LDR + r] = __uint_as_float(u & 0xffff0000u);
        }
    } else {
        const float* hp = (const float*)hin_;
        for (int idx = t; idx < 64 * F; idx += 256) {
            int r = idx / F, c = idx % F;
            xs[c * LDR + r] = hp[(size_t)(nb + r) * F + c];
        }
    }
    __syncthreads();

    const int c = t & 31;
    const int g = t >> 5;
    const float4* W4 = (const float4*)WT;
    const float4 bias = ((const float4*)biasLR)[c];
    float4 acc[8];
    #pragma unroll
    for (int u = 0; u < 8; u++) acc[u] = bias;

    #pragma unroll 2
    for (int k = 0; k < F; k++) {
        float4 w  = W4[k * 32 + c];
        float4 xa = *(const float4*)&xs[k * LDR + g * 8];
        float4 xb = *(const float4*)&xs[k * LDR + g * 8 + 4];
        acc[0].x = fmaf(xa.x, w.x, acc[0].x); acc[0].y = fmaf(xa.x, w.y, acc[0].y);
        acc[0].z = fmaf(xa.x, w.z, acc[0].z); acc[0].w = fmaf(xa.x, w.w, acc[0].w);
        acc[1].x = fmaf(xa.y, w.x, acc[1].x); acc[1].y = fmaf(xa.y, w.y, acc[1].y);
        acc[1].z = fmaf(xa.y, w.z, acc[1].z); acc[1].w = fmaf(xa.y, w.w, acc[1].w);
        acc[2].x = fmaf(xa.z, w.x, acc[2].x); acc[2].y = fmaf(xa.z, w.y, acc[2].y);
        acc[2].z = fmaf(xa.z, w.z, acc[2].z); acc[2].w = fmaf(xa.z, w.w, acc[2].w);
        acc[3].x = fmaf(xa.w, w.x, acc[3].x); acc[3].y = fmaf(xa.w, w.y, acc[3].y);
        acc[3].z = fmaf(xa.w, w.z, acc[3].z); acc[3].w = fmaf(xa.w, w.w, acc[3].w);
        acc[4].x = fmaf(xb.x, w.x, acc[4].x); acc[4].y = fmaf(xb.x, w.y, acc[4].y);
        acc[4].z = fmaf(xb.x, w.z, acc[4].z); acc[4].w = fmaf(xb.x, w.w, acc[4].w);
        acc[5].x = fmaf(xb.y, w.x, acc[5].x); acc[5].y = fmaf(xb.y, w.y, acc[5].y);
        acc[5].z = fmaf(xb.y, w.z, acc[5].z); acc[5].w = fmaf(xb.y, w.w, acc[5].w);
        acc[6].x = fmaf(xb.z, w.x, acc[6].x); acc[6].y = fmaf(xb.z, w.y, acc[6].y);
        acc[6].z = fmaf(xb.z, w.z, acc[6].z); acc[6].w = fmaf(xb.z, w.w, acc[6].w);
        acc[7].x = fmaf(xb.w, w.x, acc[7].x); acc[7].y = fmaf(xb.w, w.y, acc[7].y);
        acc[7].z = fmaf(xb.w, w.z, acc[7].z); acc[7].w = fmaf(xb.w, w.w, acc[7].w);
    }

    const int j0 = 4 * c;
    if (j0 < 64) {
        #pragma unroll
        for (int u = 0; u < 8; u++) {
            size_t row = nb + g * 8 + u;
            __half* xp = xlh + row * 64 + j0;
            *(__half2*)(xp)     = __floats2half2_rn(acc[u].x, acc[u].y);
            *(__half2*)(xp + 2) = __floats2half2_rn(acc[u].z, acc[u].w);
        }
    } else {
        #pragma unroll
        for (int u = 0; u < 8; u++) {
            size_t row = nb + g * 8 + u;
            *(float4*)(xr + row * 64 + (j0 - 64)) = acc[u];
        }
    }
}

// ---------------- score: per-edge softmax weight exp(score), clamp 60 -------
// entries [0,EE): real edges from col2; [EE,EE+NN): self edges (src=dst=i)
__global__ __launch_bounds__(256) void score_kernel(const __half* __restrict__ xlh,
                                                    const float* __restrict__ xr,
                                                    const float* __restrict__ attf,
                                                    const int2* __restrict__ col2,
                                                    int2* __restrict__ sq)
{
    int j = blockIdx.x * 256 + threadIdx.x;
    if (j >= ETOT) return;
    int src, dstn;
    if (j < EE) { int2 sd = col2[j]; src = sd.x; dstn = sd.y; }
    else        { src = dstn = j - EE; }
    const uint4* xlp = (const uint4*)(xlh + (size_t)src * 64);
    const float4* xrp = (const float4*)(xr + (size_t)dstn * 64);
    const float4* at4 = (const float4*)attf;
    float acc = 0.f;
    #pragma unroll 2
    for (int c = 0; c < 8; c++) {
        uint4 u = xlp[c];
        float2 f0 = __half22float2(*(__half2*)&u.x);
        float2 f1 = __half22float2(*(__half2*)&u.y);
        float2 f2 = __half22float2(*(__half2*)&u.z);
        float2 f3 = __half22float2(*(__half2*)&u.w);
        float4 ra = xrp[2 * c], rb = xrp[2 * c + 1];
        float4 aa = at4[2 * c], ab = at4[2 * c + 1];
        float u0 = f0.x + ra.x, u1 = f0.y + ra.y, u2 = f1.x + ra.z, u3 = f1.y + ra.w;
        float u4 = f2.x + rb.x, u5 = f2.y + rb.y, u6 = f3.x + rb.z, u7 = f3.y + rb.w;
        acc = fmaf(aa.x, fmaf(0.4f, fabsf(u0), 0.6f * u0), acc);
        acc = fmaf(aa.y, fmaf(0.4f, fabsf(u1), 0.6f * u1), acc);
        acc = fmaf(aa.z, fmaf(0.4f, fabsf(u2), 0.6f * u2), acc);
        acc = fmaf(aa.w, fmaf(0.4f, fabsf(u3), 0.6f * u3), acc);
        acc = fmaf(ab.x, fmaf(0.4f, fabsf(u4), 0.6f * u4), acc);
        acc = fmaf(ab.y, fmaf(0.4f, fabsf(u5), 0.6f * u5), acc);
        acc = fmaf(ab.z, fmaf(0.4f, fabsf(u6), 0.6f * u6), acc);
        acc = fmaf(ab.w, fmaf(0.4f, fabsf(u7), 0.6f * u7), acc);
    }
    float w = __expf(fminf(acc, 60.f));
    sq[j] = make_int2(src, __float_as_int(w));
}

// ---------------- aggregation: wave/node, 8 rows per gather instruction -----
__global__ __launch_bounds__(256) void agg3_kernel(const __half* __restrict__ xlh,
                                                   const float* __restrict__ bf,
                                                   const int* __restrict__ rowptr,
                                                   const int2* __restrict__ sq,
                                                   float* __restrict__ hout)
{
    const int lane = threadIdx.x & 63;
    const int g = lane >> 3;        // subgroup -> edge within batch
    const int r = lane & 7;         // feature octet
    int iw = blockIdx.x * 4 + (threadIdx.x >> 6);
    if (iw >= NN) return;
    const int i = __builtin_amdgcn_readfirstlane(iw);

    // self edge
    int2 qs = sq[EE + i];
    float wself = __int_as_float(qs.y);
    uint4 srow = *(const uint4*)(xlh + (size_t)i * 64 + r * 8);
    float2 s0 = __half22float2(*(__half2*)&srow.x);
    float2 s1 = __half22float2(*(__half2*)&srow.y);
    float2 s2 = __half22float2(*(__half2*)&srow.z);
    float2 s3 = __half22float2(*(__half2*)&srow.w);

    float acc[8];
    float denom;
    if (g == 0) {
        acc[0] = wself * s0.x; acc[1] = wself * s0.y;
        acc[2] = wself * s1.x; acc[3] = wself * s1.y;
        acc[4] = wself * s2.x; acc[5] = wself * s2.y;
        acc[6] = wself * s3.x; acc[7] = wself * s3.y;
        denom = wself;
    } else {
        #pragma unroll
        for (int k = 0; k < 8; k++) acc[k] = 0.f;
        denom = 0.f;
    }

    const int e0 = rowptr[i], e1 = rowptr[i + 1];
    const int n = e1 - e0;
    const int eL = e1 - 1;

    for (int base = 0; base < n; base += 16) {
        const int j = e0 + base;
        int2 qa = sq[min(j + g, eL)];
        int2 qb = sq[min(j + 8 + g, eL)];
        uint4 ra = *(const uint4*)(xlh + (size_t)qa.x * 64 + r * 8);
        uint4 rb = *(const uint4*)(xlh + (size_t)qb.x * 64 + r * 8);
        float wa = (base + g < n)     ? __int_as_float(qa.y) : 0.f;
        float wb = (base + 8 + g < n) ? __int_as_float(qb.y) : 0.f;

        float2 a0 = __half22float2(*(__half2*)&ra.x);
        float2 a1 = __half22float2(*(__half2*)&ra.y);
        float2 a2 = __half22float2(*(__half2*)&ra.z);
        float2 a3 = __half22float2(*(__half2*)&ra.w);
        float2 b0 = __half22float2(*(__half2*)&rb.x);
        float2 b1 = __half22float2(*(__half2*)&rb.y);
        float2 b2 = __half22float2(*(__half2*)&rb.z);
        float2 b3 = __half22float2(*(__half2*)&rb.w);

        acc[0] = fmaf(wa, a0.x, acc[0]); acc[1] = fmaf(wa, a0.y, acc[1]);
        acc[2] = fmaf(wa, a1.x, acc[2]); acc[3] = fmaf(wa, a1.y, acc[3]);
        acc[4] = fmaf(wa, a2.x, acc[4]); acc[5] = fmaf(wa, a2.y, acc[5]);
        acc[6] = fmaf(wa, a3.x, acc[6]); acc[7] = fmaf(wa, a3.y, acc[7]);
        acc[0] = fmaf(wb, b0.x, acc[0]); acc[1] = fmaf(wb, b0.y, acc[1]);
        acc[2] = fmaf(wb, b1.x, acc[2]); acc[3] = fmaf(wb, b1.y, acc[3]);
        acc[4] = fmaf(wb, b2.x, acc[4]); acc[5] = fmaf(wb, b2.y, acc[5]);
        acc[6] = fmaf(wb, b3.x, acc[6]); acc[7] = fmaf(wb, b3.y, acc[7]);
        denom += wa + wb;
    }

    // reduce across the 8 subgroups (lanes differing in bits 3..5)
    #pragma unroll
    for (int off = 8; off < 64; off <<= 1) {
        #pragma unroll
        for (int k = 0; k < 8; k++) acc[k] += __shfl_xor(acc[k], off, 64);
        denom += __shfl_xor(denom, off, 64);
    }

    if (g == 0) {
        float inv = 1.f / denom;
        float4 bfa = *(const float4*)(bf + r * 8);
        float4 bfb = *(const float4*)(bf + r * 8 + 4);
        float o0 = fmaxf(fmaf(acc[0], inv, bfa.x), 0.f);
        float o1 = fmaxf(fmaf(acc[1], inv, bfa.y), 0.f);
        float o2 = fmaxf(fmaf(acc[2], inv, bfa.z), 0.f);
        float o3 = fmaxf(fmaf(acc[3], inv, bfa.w), 0.f);
        float o4 = fmaxf(fmaf(acc[4], inv, bfb.x), 0.f);
        float o5 = fmaxf(fmaf(acc[5], inv, bfb.y), 0.f);
        float o6 = fmaxf(fmaf(acc[6], inv, bfb.z), 0.f);
        float o7 = fmaxf(fmaf(acc[7], inv, bfb.w), 0.f);
        float* op = hout + (size_t)i * 64 + r * 8;
        *(float4*)(op)     = make_float4(o0, o1, o2, o3);
        *(float4*)(op + 4) = make_float4(o4, o5, o6, o7);
    }
}

// ---------------- readout: wave per node, 10 butterfly dots ----------------
__global__ __launch_bounds__(256) void readout_kernel(const float* __restrict__ h,
                                                      const float* __restrict__ WROf,
                                                      const float* __restrict__ brof,
                                                      void* __restrict__ out,
                                                      const int* __restrict__ flagp)
{
    const int lane = threadIdx.x & 63;
    const int i = blockIdx.x * 4 + (threadIdx.x >> 6);
    if (i >= NN) return;
    const int f = flagp[0];
    float hv = h[(size_t)i * 64 + lane];
    float res = 0.f;
    #pragma unroll
    for (int o = 0; o < OUTD; o++) {
        float p = hv * WROf[o * 64 + lane];
        #pragma unroll
        for (int off = 1; off < 64; off <<= 1) p += __shfl_xor(p, off, 64);
        if (lane == o) res = p + brof[o];
    }
    if (lane < OUTD) {
        if (f) ((bf16*)out)[(size_t)i * OUTD + lane] = __float2bfloat16(res);
        else   ((float*)out)[(size_t)i * OUTD + lane] = res;
    }
}

extern "C" void kernel_launch(void* const* d_in, const int* in_sizes, int n_in,
                              void* d_out, int out_size, void* d_ws, size_t ws_size,
                              hipStream_t stream) {
    const void* x   = d_in[0];
    const int* ei   = (const int*)d_in[1];
    const void* Wl0 = d_in[3];  const void* bl0 = d_in[4];
    const void* Wr0 = d_in[5];  const void* br0 = d_in[6];
    const void* at0 = d_in[7];  const void* b0  = d_in[8];
    const void* Wl1 = d_in[9];  const void* bl1 = d_in[10];
    const void* Wr1 = d_in[11]; const void* br1 = d_in[12];
    const void* at1 = d_in[13]; const void* b1  = d_in[14];
    const void* Wl2 = d_in[15]; const void* bl2 = d_in[16];
    const void* Wr2 = d_in[17]; const void* br2 = d_in[18];
    const void* at2 = d_in[19]; const void* b2  = d_in[20];
    const void* Wro = d_in[21]; const void* bro = d_in[22];

    const int* srcArr = ei;
    const int* dstArr = ei + EE;

    float* wf = (float*)d_ws;
    float* WT0   = wf;                        // 16384
    float* WT1   = wf + 16384;                // 8192
    float* WT2   = wf + 24576;                // 8192
    float* small = wf + 32768;                // 1536
    int*   flag  = (int*)(wf + 34304);        // pad 64
    int*   rowptr = (int*)(wf + 34368);       // 80001 (pad 80128)
    int*   bsums  = (int*)(wf + 114496);      // 512
    int*   fillc  = (int*)(wf + 115008);      // 80000 (per-dst counts)
    int*   bucket_cnt  = (int*)(wf + 195008); // 128
    int*   bucket_base = (int*)(wf + 195136); // 128 (+1 used)
    int*   chunkcnt    = (int*)(wf + 195264); // NBUK*NCH = 49375 (pad 49472)
    int2*  part   = (int2*)(wf + 244736);     // EE int2 = 2560000 ints
    int2*  col2   = (int2*)(wf + 2804736);    // 2560000
    int2*  sq     = (int2*)(wf + 5364736);    // (EE+NN) int2 = 2720000 ints
    __half* xlh   = (__half*)(wf + 8084736);  // NN*64 halves = 2560000 floats
    float* xr = wf + 10644736;                // 5120000
    float* hA = xr + (size_t)NN * 64;         // 5120000 (ends 20,884,736 floats)

    float* biasLR0 = small;        float* biasLR1 = small + 128; float* biasLR2 = small + 256;
    float* attf0 = small + 384;    float* attf1 = small + 448;   float* attf2 = small + 512;
    float* bf0   = small + 576;    float* bf1   = small + 640;   float* bf2   = small + 704;
    float* WROf  = small + 768;    float* brof  = small + 1408;

    detect_kernel<<<dim3(1), dim3(64), 0, stream>>>((const unsigned*)Wl0, flag);

    preconvert<<<dim3(134), dim3(256), 0, stream>>>(
        Wl0, Wr0, Wl1, Wr1, Wl2, Wr2, bl0, br0, bl1, br1, bl2, br2,
        at0, at1, at2, b0, b1, b2, Wro, bro, WT0, WT1, WT2, small, flag);

    // deterministic edge sort
    chunkhist_kernel<<<dim3(NCH), dim3(256), 0, stream>>>(dstArr, chunkcnt);
    cscan_kernel<<<dim3(NBUK), dim3(1024), 0, stream>>>(chunkcnt, bucket_cnt);
    bscan_kernel<<<dim3(1), dim3(128), 0, stream>>>(bucket_cnt, bucket_base);
    part_kernel<<<dim3(NCH), dim3(256), 0, stream>>>(srcArr, dstArr, chunkcnt, bucket_base, part);
    hist_part_kernel<<<dim3(NBUK), dim3(256), 0, stream>>>(part, bucket_base, fillc);
    scan1<<<dim3(313), dim3(256), 0, stream>>>(fillc, rowptr, bsums);
    scan2<<<dim3(1), dim3(512), 0, stream>>>(bsums, 313);
    scan3<<<dim3(313), dim3(256), 0, stream>>>(rowptr, bsums);
    scatter2_kernel<<<dim3(NBUK), dim3(256), 0, stream>>>(part, bucket_base, rowptr, col2);

    const int SGRID = (ETOT + 255) / 256;

    // layer 0
    lin_fast<128, true><<<dim3(NN / 64), dim3(256), 0, stream>>>(x, WT0, biasLR0, xlh, xr, flag);
    score_kernel<<<dim3(SGRID), dim3(256), 0, stream>>>(xlh, xr, attf0, col2, sq);
    agg3_kernel<<<dim3(NN / 4), dim3(256), 0, stream>>>(xlh, bf0, rowptr, sq, hA);
    // layer 1
    lin_fast<64, false><<<dim3(NN / 64), dim3(256), 0, stream>>>(hA, WT1, biasLR1, xlh, xr, flag);
    score_kernel<<<dim3(SGRID), dim3(256), 0, stream>>>(xlh, xr, attf1, col2, sq);
    agg3_kernel<<<dim3(NN / 4), dim3(256), 0, stream>>>(xlh, bf1, rowptr, sq, hA);
    // layer 2
    lin_fast<64, false><<<dim3(NN / 64), dim3(256), 0, stream>>>(hA, WT2, biasLR2, xlh, xr, flag);
    score_kernel<<<dim3(SGRID), dim3(256), 0, stream>>>(xlh, xr, attf2, col2, sq);
    agg3_kernel<<<dim3(NN / 4), dim3(256), 0, stream>>>(xlh, bf2, rowptr, sq, hA);

    // readout
    readout_kernel<<<dim3(NN / 4), dim3(256), 0, stream>>>(hA, WROf, brof, d_out, flag);
}

// Round 12
// 550.760 us; speedup vs baseline: 1.1274x; 1.0707x over previous
//
#include <hip/hip_runtime.h>
#include <hip/hip_bf16.h>
#include <hip/hip_fp16.h>

// GATv2 3-layer, N=80000 E=1280000 FIN=128 H=64 OUT=10. fp32 compute.
// Round 12: fix round-11 bug (wsh fill used `if(tid<640)` in a 256-thread
// block -> 384 uninitialized LDS entries). Now strided fill. Readout is
// thread-per-node serial dot, zero cross-lane ops. Everything else unchanged.

#define NN 80000
#define EE 1280000
#define ETOT (EE + NN)
#define FIN 128
#define HH 64
#define OUTD 10
#define NBUK 79            // dst>>10 buckets (79*1024 >= 80000)
#define PCH 2048           // edges per partition chunk
#define NCH 625            // EE / PCH

typedef __hip_bfloat16 bf16;

__device__ __forceinline__ float ldw(const void* p, int i, int f) {
    return f ? __bfloat162float(((const bf16*)p)[i]) : ((const float*)p)[i];
}

// ---------------- dtype detect ----------------
__global__ void detect_kernel(const unsigned* __restrict__ w, int* __restrict__ flag) {
    int lane = threadIdx.x;
    int big = 0;
    for (int i = lane; i < 2048; i += 64) {
        unsigned u = w[i];
        float a = __uint_as_float(u << 16);
        float b = __uint_as_float(u & 0xffff0000u);
        if (!(fabsf(a) <= 1024.f)) big = 1;
        if (!(fabsf(b) <= 1024.f)) big = 1;
    }
    big = (__ballot(big) != 0ull) ? 1 : 0;
    if (lane == 0) flag[0] = big ? 0 : 1;     // 1 = bf16 storage, 0 = fp32
}

// ---------------- preconvert weights: WT[k*128 + j] ----------------
__global__ void preconvert(
    const void* Wl0, const void* Wr0, const void* Wl1, const void* Wr1,
    const void* Wl2, const void* Wr2,
    const void* bl0, const void* br0, const void* bl1, const void* br1,
    const void* bl2, const void* br2,
    const void* att0, const void* att1, const void* att2,
    const void* b0, const void* b1, const void* b2,
    const void* Wro, const void* bro,
    float* WT0, float* WT1, float* WT2, float* small,
    const int* __restrict__ flagp)
{
    const int f = flagp[0];
    int t = blockIdx.x * 256 + threadIdx.x;
    if (t < 16384) {
        int j = t & 127, k = t >> 7;
        float v = (j < 64) ? ldw(Wl0, j * 128 + k, f) : ldw(Wr0, (j - 64) * 128 + k, f);
        WT0[k * 128 + j] = v;
    } else if (t < 24576) {
        int u = t - 16384; int j = u & 127, k = u >> 7;
        float v = (j < 64) ? ldw(Wl1, j * 64 + k, f) : ldw(Wr1, (j - 64) * 64 + k, f);
        WT1[k * 128 + j] = v;
    } else if (t < 32768) {
        int u = t - 24576; int j = u & 127, k = u >> 7;
        float v = (j < 64) ? ldw(Wl2, j * 64 + k, f) : ldw(Wr2, (j - 64) * 64 + k, f);
        WT2[k * 128 + j] = v;
    } else if (t < 34304) {
        int s = t - 32768;
        const void* BL[3] = { bl0, bl1, bl2 };
        const void* BR[3] = { br0, br1, br2 };
        const void* AT[3] = { att0, att1, att2 };
        const void* BB[3] = { b0, b1, b2 };
        float v = 0.f;
        if (s < 384) {
            int l = s / 128, r = s % 128;
            v = (r < 64) ? ldw(BL[l], r, f) : ldw(BR[l], r - 64, f);
        } else if (s < 576) {
            int q = s - 384; v = ldw(AT[q / 64], q % 64, f);
        } else if (s < 768) {
            int q = s - 576; v = ldw(BB[q / 64], q % 64, f);
        } else if (s < 1408) {
            v = ldw(Wro, s - 768, f);
        } else if (s < 1418) {
            v = ldw(bro, s - 1408, f);
        } else return;
        small[s] = v;
    }
}

// ---------------- A: per-chunk bucket histogram ----------------
__global__ __launch_bounds__(256) void chunkhist_kernel(const int* __restrict__ dst,
                                                        int* __restrict__ chunkcnt)
{
    __shared__ int h[NBUK];
    const int tid = threadIdx.x, c = blockIdx.x;
    for (int i = tid; i < NBUK; i += 256) h[i] = 0;
    __syncthreads();
    const int e0 = c * PCH + tid * 8;
    int4 a = *(const int4*)(dst + e0);
    int4 b = *(const int4*)(dst + e0 + 4);
    atomicAdd(&h[a.x >> 10], 1); atomicAdd(&h[a.y >> 10], 1);
    atomicAdd(&h[a.z >> 10], 1); atomicAdd(&h[a.w >> 10], 1);
    atomicAdd(&h[b.x >> 10], 1); atomicAdd(&h[b.y >> 10], 1);
    atomicAdd(&h[b.z >> 10], 1); atomicAdd(&h[b.w >> 10], 1);
    __syncthreads();
    for (int i = tid; i < NBUK; i += 256) chunkcnt[i * NCH + c] = h[i];
}

// ---------------- B1: per-bucket exclusive scan over chunk counts ----------
__global__ __launch_bounds__(1024) void cscan_kernel(int* __restrict__ chunkcnt,
                                                     int* __restrict__ bucket_cnt)
{
    __shared__ int s[1024];
    const int b = blockIdx.x, t = threadIdx.x;
    int v = (t < NCH) ? chunkcnt[b * NCH + t] : 0;
    s[t] = v;
    __syncthreads();
    #pragma unroll
    for (int off = 1; off < 1024; off <<= 1) {
        int u = (t >= off) ? s[t - off] : 0;
        __syncthreads();
        s[t] += u;
        __syncthreads();
    }
    if (t < NCH) chunkcnt[b * NCH + t] = s[t] - v;
    if (t == NCH - 1) bucket_cnt[b] = s[t];
}

// ---------------- B2: scan buckets -> bucket_base ----------------
__global__ void bscan_kernel(const int* __restrict__ bucket_cnt,
                             int* __restrict__ bucket_base)
{
    __shared__ int sc[128];
    const int t = threadIdx.x;
    sc[t] = (t < NBUK) ? bucket_cnt[t] : 0;
    __syncthreads();
    #pragma unroll
    for (int off = 1; off < 128; off <<= 1) {
        int v = (t >= off) ? sc[t - off] : 0;
        __syncthreads();
        sc[t] += v;
        __syncthreads();
    }
    if (t < NBUK) bucket_base[t] = (t == 0) ? 0 : sc[t - 1];
    if (t == 0) bucket_base[NBUK] = sc[NBUK - 1];
}

// ---------------- C: deterministic partition into buckets -------------------
__global__ __launch_bounds__(256) void part_kernel(const int* __restrict__ src,
                                                   const int* __restrict__ dst,
                                                   const int* __restrict__ chunkcnt,
                                                   const int* __restrict__ bucket_base,
                                                   int2* __restrict__ part)
{
    __shared__ int hcnt[NBUK];
    __shared__ int sc[128];
    __shared__ int hbase[NBUK + 1];
    __shared__ int hpos[NBUK];
    __shared__ int hgb[NBUK];
    __shared__ int2 stage[PCH];
    const int tid = threadIdx.x, c = blockIdx.x;

    for (int i = tid; i < NBUK; i += 256) hcnt[i] = 0;
    __syncthreads();

    const int e0 = c * PCH + tid * 8;
    int4 sa = *(const int4*)(src + e0);
    int4 sb = *(const int4*)(src + e0 + 4);
    int4 da = *(const int4*)(dst + e0);
    int4 db = *(const int4*)(dst + e0 + 4);
    int dv[8] = { da.x, da.y, da.z, da.w, db.x, db.y, db.z, db.w };
    int sv[8] = { sa.x, sa.y, sa.z, sa.w, sb.x, sb.y, sb.z, sb.w };
    #pragma unroll
    for (int u = 0; u < 8; u++) atomicAdd(&hcnt[dv[u] >> 10], 1);
    __syncthreads();

    if (tid < 128) sc[tid] = (tid < NBUK) ? hcnt[tid] : 0;
    __syncthreads();
    #pragma unroll
    for (int off = 1; off < 128; off <<= 1) {
        int v = (tid < 128 && tid >= off) ? sc[tid - off] : 0;
        __syncthreads();
        if (tid < 128) sc[tid] += v;
        __syncthreads();
    }
    if (tid < NBUK) {
        int b = (tid == 0) ? 0 : sc[tid - 1];
        hbase[tid] = b;
        hpos[tid] = b;
        hgb[tid] = bucket_base[tid] + chunkcnt[tid * NCH + c];
    }
    if (tid == 0) hbase[NBUK] = PCH;
    __syncthreads();

    #pragma unroll
    for (int u = 0; u < 8; u++) {
        int p = atomicAdd(&hpos[dv[u] >> 10], 1);
        stage[p] = make_int2(sv[u], dv[u]);
    }
    __syncthreads();

    for (int s = tid; s < PCH; s += 256) {
        int lo = 0, hi = NBUK;
        #pragma unroll
        for (int it = 0; it < 7; it++) {
            int mid = (lo + hi) >> 1;
            if (hbase[mid] <= s) lo = mid; else hi = mid;
        }
        part[hgb[lo] + (s - hbase[lo])] = stage[s];
    }
}

// ---------------- fine hist: one block per bucket, LDS counters -------------
__global__ __launch_bounds__(256) void hist_part_kernel(const int2* __restrict__ part,
                                                        const int* __restrict__ bucket_base,
                                                        int* __restrict__ cnt)
{
    __shared__ int lcnt[1024];
    const int b = blockIdx.x, tid = threadIdx.x;
    const int dbase = b << 10;
    for (int i = tid; i < 1024; i += 256) lcnt[i] = 0;
    __syncthreads();
    const int eb = bucket_base[b], ee = bucket_base[b + 1];
    for (int e = eb + tid; e < ee; e += 256)
        atomicAdd(&lcnt[part[e].y - dbase], 1);
    __syncthreads();
    const int nd = min(1024, NN - dbase);
    for (int i = tid; i < nd; i += 256) cnt[dbase + i] = lcnt[i];
}

// ---------------- scans ----------------
__global__ void scan1(const int* __restrict__ cnt, int* __restrict__ rowptr,
                      int* __restrict__ bsums) {
    __shared__ int sh[256];
    int i = blockIdx.x * 256 + threadIdx.x;
    int tid = threadIdx.x;
    int c = (i < NN) ? cnt[i] : 0;
    sh[tid] = c;
    __syncthreads();
    #pragma unroll
    for (int off = 1; off < 256; off <<= 1) {
        int t = (tid >= off) ? sh[tid - off] : 0;
        __syncthreads();
        sh[tid] += t;
        __syncthreads();
    }
    if (i < NN) rowptr[i + 1] = sh[tid];
    if (tid == 255) bsums[blockIdx.x] = sh[255];
}

__global__ void scan2(int* __restrict__ bsums, int nb) {
    __shared__ int sh[512];
    int t = threadIdx.x;
    sh[t] = (t < nb) ? bsums[t] : 0;
    __syncthreads();
    #pragma unroll
    for (int off = 1; off < 512; off <<= 1) {
        int v = (t >= off) ? sh[t - off] : 0;
        __syncthreads();
        sh[t] += v;
        __syncthreads();
    }
    if (t < nb) bsums[t] = sh[t];
}

__global__ void scan3(int* __restrict__ rowptr, const int* __restrict__ bsums) {
    int i = blockIdx.x * 256 + threadIdx.x;
    if (i == 0) rowptr[0] = 0;
    int add = (blockIdx.x == 0) ? 0 : bsums[blockIdx.x - 1];
    if (i < NN) rowptr[i + 1] += add;
}

// ---------------- P2: fine scatter, one block per bucket --------------------
__global__ __launch_bounds__(256) void scatter2_kernel(const int2* __restrict__ part,
                                                       const int* __restrict__ bucket_base,
                                                       const int* __restrict__ rowptr,
                                                       int2* __restrict__ col2)
{
    __shared__ int lfill[1024];
    const int b = blockIdx.x, tid = threadIdx.x;
    const int dbase = b << 10;
    const int nd = min(1024, NN - dbase);
    for (int i = tid; i < nd; i += 256) lfill[i] = rowptr[dbase + i];
    __syncthreads();
    const int eb = bucket_base[b], ee = bucket_base[b + 1];
    for (int e = eb + tid; e < ee; e += 256) {
        int2 sd = part[e];
        int pos = atomicAdd(&lfill[sd.y - dbase], 1);
        col2[pos] = sd;
    }
}

// ---------------- linear: xl (fp16) | xr (fp32) ----------------
template<int F, bool L0>
__global__ __launch_bounds__(256) void lin_fast(const void* __restrict__ hin_,
                                                const float* __restrict__ WT,
                                                const float* __restrict__ biasLR,
                                                __half* __restrict__ xlh,
                                                float* __restrict__ xr,
                                                const int* __restrict__ flagp)
{
    constexpr int LDR = 72;
    __shared__ __align__(16) float xs[F * LDR];
    const int t = threadIdx.x;
    const int nb = blockIdx.x * 64;

    if (L0 && flagp[0]) {
        const unsigned* hp = (const unsigned*)hin_;
        for (int idx = t; idx < 64 * (F / 2); idx += 256) {
            int r = idx / (F / 2), c = idx % (F / 2);
            unsigned u = hp[(size_t)(nb + r) * (F / 2) + c];
            xs[(2 * c) * LDR + r]     = __uint_as_float(u << 16);
            xs[(2 * c + 1) * LDR + r] = __uint_as_float(u & 0xffff0000u);
        }
    } else {
        const float* hp = (const float*)hin_;
        for (int idx = t; idx < 64 * F; idx += 256) {
            int r = idx / F, c = idx % F;
            xs[c * LDR + r] = hp[(size_t)(nb + r) * F + c];
        }
    }
    __syncthreads();

    const int c = t & 31;
    const int g = t >> 5;
    const float4* W4 = (const float4*)WT;
    const float4 bias = ((const float4*)biasLR)[c];
    float4 acc[8];
    #pragma unroll
    for (int u = 0; u < 8; u++) acc[u] = bias;

    #pragma unroll 2
    for (int k = 0; k < F; k++) {
        float4 w  = W4[k * 32 + c];
        float4 xa = *(const float4*)&xs[k * LDR + g * 8];
        float4 xb = *(const float4*)&xs[k * LDR + g * 8 + 4];
        acc[0].x = fmaf(xa.x, w.x, acc[0].x); acc[0].y = fmaf(xa.x, w.y, acc[0].y);
        acc[0].z = fmaf(xa.x, w.z, acc[0].z); acc[0].w = fmaf(xa.x, w.w, acc[0].w);
        acc[1].x = fmaf(xa.y, w.x, acc[1].x); acc[1].y = fmaf(xa.y, w.y, acc[1].y);
        acc[1].z = fmaf(xa.y, w.z, acc[1].z); acc[1].w = fmaf(xa.y, w.w, acc[1].w);
        acc[2].x = fmaf(xa.z, w.x, acc[2].x); acc[2].y = fmaf(xa.z, w.y, acc[2].y);
        acc[2].z = fmaf(xa.z, w.z, acc[2].z); acc[2].w = fmaf(xa.z, w.w, acc[2].w);
        acc[3].x = fmaf(xa.w, w.x, acc[3].x); acc[3].y = fmaf(xa.w, w.y, acc[3].y);
        acc[3].z = fmaf(xa.w, w.z, acc[3].z); acc[3].w = fmaf(xa.w, w.w, acc[3].w);
        acc[4].x = fmaf(xb.x, w.x, acc[4].x); acc[4].y = fmaf(xb.x, w.y, acc[4].y);
        acc[4].z = fmaf(xb.x, w.z, acc[4].z); acc[4].w = fmaf(xb.x, w.w, acc[4].w);
        acc[5].x = fmaf(xb.y, w.x, acc[5].x); acc[5].y = fmaf(xb.y, w.y, acc[5].y);
        acc[5].z = fmaf(xb.y, w.z, acc[5].z); acc[5].w = fmaf(xb.y, w.w, acc[5].w);
        acc[6].x = fmaf(xb.z, w.x, acc[6].x); acc[6].y = fmaf(xb.z, w.y, acc[6].y);
        acc[6].z = fmaf(xb.z, w.z, acc[6].z); acc[6].w = fmaf(xb.z, w.w, acc[6].w);
        acc[7].x = fmaf(xb.w, w.x, acc[7].x); acc[7].y = fmaf(xb.w, w.y, acc[7].y);
        acc[7].z = fmaf(xb.w, w.z, acc[7].z); acc[7].w = fmaf(xb.w, w.w, acc[7].w);
    }

    const int j0 = 4 * c;
    if (j0 < 64) {
        #pragma unroll
        for (int u = 0; u < 8; u++) {
            size_t row = nb + g * 8 + u;
            __half* xp = xlh + row * 64 + j0;
            *(__half2*)(xp)     = __floats2half2_rn(acc[u].x, acc[u].y);
            *(__half2*)(xp + 2) = __floats2half2_rn(acc[u].z, acc[u].w);
        }
    } else {
        #pragma unroll
        for (int u = 0; u < 8; u++) {
            size_t row = nb + g * 8 + u;
            *(float4*)(xr + row * 64 + (j0 - 64)) = acc[u];
        }
    }
}

// ---------------- score: per-edge softmax weight exp(score), clamp 60 -------
// entries [0,EE): real edges from col2; [EE,EE+NN): self edges (src=dst=i)
__global__ __launch_bounds__(256) void score_kernel(const __half* __restrict__ xlh,
                                                    const float* __restrict__ xr,
                                                    const float* __restrict__ attf,
                                                    const int2* __restrict__ col2,
                                                    int2* __restrict__ sq)
{
    int j = blockIdx.x * 256 + threadIdx.x;
    if (j >= ETOT) return;
    int src, dstn;
    if (j < EE) { int2 sd = col2[j]; src = sd.x; dstn = sd.y; }
    else        { src = dstn = j - EE; }
    const uint4* xlp = (const uint4*)(xlh + (size_t)src * 64);
    const float4* xrp = (const float4*)(xr + (size_t)dstn * 64);
    const float4* at4 = (const float4*)attf;
    float acc = 0.f;
    #pragma unroll 2
    for (int c = 0; c < 8; c++) {
        uint4 u = xlp[c];
        float2 f0 = __half22float2(*(__half2*)&u.x);
        float2 f1 = __half22float2(*(__half2*)&u.y);
        float2 f2 = __half22float2(*(__half2*)&u.z);
        float2 f3 = __half22float2(*(__half2*)&u.w);
        float4 ra = xrp[2 * c], rb = xrp[2 * c + 1];
        float4 aa = at4[2 * c], ab = at4[2 * c + 1];
        float u0 = f0.x + ra.x, u1 = f0.y + ra.y, u2 = f1.x + ra.z, u3 = f1.y + ra.w;
        float u4 = f2.x + rb.x, u5 = f2.y + rb.y, u6 = f3.x + rb.z, u7 = f3.y + rb.w;
        acc = fmaf(aa.x, fmaf(0.4f, fabsf(u0), 0.6f * u0), acc);
        acc = fmaf(aa.y, fmaf(0.4f, fabsf(u1), 0.6f * u1), acc);
        acc = fmaf(aa.z, fmaf(0.4f, fabsf(u2), 0.6f * u2), acc);
        acc = fmaf(aa.w, fmaf(0.4f, fabsf(u3), 0.6f * u3), acc);
        acc = fmaf(ab.x, fmaf(0.4f, fabsf(u4), 0.6f * u4), acc);
        acc = fmaf(ab.y, fmaf(0.4f, fabsf(u5), 0.6f * u5), acc);
        acc = fmaf(ab.z, fmaf(0.4f, fabsf(u6), 0.6f * u6), acc);
        acc = fmaf(ab.w, fmaf(0.4f, fabsf(u7), 0.6f * u7), acc);
    }
    float w = __expf(fminf(acc, 60.f));
    sq[j] = make_int2(src, __float_as_int(w));
}

// ---------------- aggregation: wave/node, 8 rows per gather instruction -----
__global__ __launch_bounds__(256) void agg3_kernel(const __half* __restrict__ xlh,
                                                   const float* __restrict__ bf,
                                                   const int* __restrict__ rowptr,
                                                   const int2* __restrict__ sq,
                                                   float* __restrict__ hout)
{
    const int lane = threadIdx.x & 63;
    const int g = lane >> 3;        // subgroup -> edge within batch
    const int r = lane & 7;         // feature octet
    int iw = blockIdx.x * 4 + (threadIdx.x >> 6);
    if (iw >= NN) return;
    const int i = __builtin_amdgcn_readfirstlane(iw);

    // self edge
    int2 qs = sq[EE + i];
    float wself = __int_as_float(qs.y);
    uint4 srow = *(const uint4*)(xlh + (size_t)i * 64 + r * 8);
    float2 s0 = __half22float2(*(__half2*)&srow.x);
    float2 s1 = __half22float2(*(__half2*)&srow.y);
    float2 s2 = __half22float2(*(__half2*)&srow.z);
    float2 s3 = __half22float2(*(__half2*)&srow.w);

    float acc[8];
    float denom;
    if (g == 0) {
        acc[0] = wself * s0.x; acc[1] = wself * s0.y;
        acc[2] = wself * s1.x; acc[3] = wself * s1.y;
        acc[4] = wself * s2.x; acc[5] = wself * s2.y;
        acc[6] = wself * s3.x; acc[7] = wself * s3.y;
        denom = wself;
    } else {
        #pragma unroll
        for (int k = 0; k < 8; k++) acc[k] = 0.f;
        denom = 0.f;
    }

    const int e0 = rowptr[i], e1 = rowptr[i + 1];
    const int n = e1 - e0;
    const int eL = e1 - 1;

    for (int base = 0; base < n; base += 16) {
        const int j = e0 + base;
        int2 qa = sq[min(j + g, eL)];
        int2 qb = sq[min(j + 8 + g, eL)];
        uint4 ra = *(const uint4*)(xlh + (size_t)qa.x * 64 + r * 8);
        uint4 rb = *(const uint4*)(xlh + (size_t)qb.x * 64 + r * 8);
        float wa = (base + g < n)     ? __int_as_float(qa.y) : 0.f;
        float wb = (base + 8 + g < n) ? __int_as_float(qb.y) : 0.f;

        float2 a0 = __half22float2(*(__half2*)&ra.x);
        float2 a1 = __half22float2(*(__half2*)&ra.y);
        float2 a2 = __half22float2(*(__half2*)&ra.z);
        float2 a3 = __half22float2(*(__half2*)&ra.w);
        float2 b0 = __half22float2(*(__half2*)&rb.x);
        float2 b1 = __half22float2(*(__half2*)&rb.y);
        float2 b2 = __half22float2(*(__half2*)&rb.z);
        float2 b3 = __half22float2(*(__half2*)&rb.w);

        acc[0] = fmaf(wa, a0.x, acc[0]); acc[1] = fmaf(wa, a0.y, acc[1]);
        acc[2] = fmaf(wa, a1.x, acc[2]); acc[3] = fmaf(wa, a1.y, acc[3]);
        acc[4] = fmaf(wa, a2.x, acc[4]); acc[5] = fmaf(wa, a2.y, acc[5]);
        acc[6] = fmaf(wa, a3.x, acc[6]); acc[7] = fmaf(wa, a3.y, acc[7]);
        acc[0] = fmaf(wb, b0.x, acc[0]); acc[1] = fmaf(wb, b0.y, acc[1]);
        acc[2] = fmaf(wb, b1.x, acc[2]); acc[3] = fmaf(wb, b1.y, acc[3]);
        acc[4] = fmaf(wb, b2.x, acc[4]); acc[5] = fmaf(wb, b2.y, acc[5]);
        acc[6] = fmaf(wb, b3.x, acc[6]); acc[7] = fmaf(wb, b3.y, acc[7]);
        denom += wa + wb;
    }

    // reduce across the 8 subgroups (lanes differing in bits 3..5)
    #pragma unroll
    for (int off = 8; off < 64; off <<= 1) {
        #pragma unroll
        for (int k = 0; k < 8; k++) acc[k] += __shfl_xor(acc[k], off, 64);
        denom += __shfl_xor(denom, off, 64);
    }

    if (g == 0) {
        float inv = 1.f / denom;
        float4 bfa = *(const float4*)(bf + r * 8);
        float4 bfb = *(const float4*)(bf + r * 8 + 4);
        float o0 = fmaxf(fmaf(acc[0], inv, bfa.x), 0.f);
        float o1 = fmaxf(fmaf(acc[1], inv, bfa.y), 0.f);
        float o2 = fmaxf(fmaf(acc[2], inv, bfa.z), 0.f);
        float o3 = fmaxf(fmaf(acc[3], inv, bfa.w), 0.f);
        float o4 = fmaxf(fmaf(acc[4], inv, bfb.x), 0.f);
        float o5 = fmaxf(fmaf(acc[5], inv, bfb.y), 0.f);
        float o6 = fmaxf(fmaf(acc[6], inv, bfb.z), 0.f);
        float o7 = fmaxf(fmaf(acc[7], inv, bfb.w), 0.f);
        float* op = hout + (size_t)i * 64 + r * 8;
        *(float4*)(op)     = make_float4(o0, o1, o2, o3);
        *(float4*)(op + 4) = make_float4(o4, o5, o6, o7);
    }
}

// ---------------- readout: thread-per-node serial dot, Wro^T in LDS --------
__global__ __launch_bounds__(256) void readout2_kernel(const float* __restrict__ h,
                                                       const float* __restrict__ WROf,
                                                       const float* __restrict__ brof,
                                                       void* __restrict__ out,
                                                       const int* __restrict__ flagp)
{
    __shared__ float wsh[640];   // wsh[k*10+o] = Wro[o][k]
    __shared__ float bsh[OUTD];
    const int tid = threadIdx.x;
    for (int idx = tid; idx < 640; idx += 256) {
        int k = idx / 10, o = idx % 10;
        wsh[idx] = WROf[o * 64 + k];
    }
    if (tid < OUTD) bsh[tid] = brof[tid];
    __syncthreads();

    const int i = blockIdx.x * 256 + tid;
    if (i >= NN) return;
    const int f = flagp[0];

    float res[OUTD];
    #pragma unroll
    for (int o = 0; o < OUTD; o++) res[o] = bsh[o];

    const float4* h4 = (const float4*)(h + (size_t)i * 64);
    #pragma unroll 4
    for (int c = 0; c < 16; c++) {
        float4 hv = h4[c];
        const float* wp = &wsh[c * 40];
        #pragma unroll
        for (int o = 0; o < OUTD; o++) {
            float t = fmaf(hv.x, wp[o], fmaf(hv.y, wp[10 + o],
                      fmaf(hv.z, wp[20 + o], hv.w * wp[30 + o])));
            res[o] += t;
        }
    }

    if (f) {
        bf16* op = (bf16*)out + (size_t)i * OUTD;
        #pragma unroll
        for (int o = 0; o < OUTD; o++) op[o] = __float2bfloat16(res[o]);
    } else {
        float* op = (float*)out + (size_t)i * OUTD;
        #pragma unroll
        for (int o = 0; o < OUTD; o++) op[o] = res[o];
    }
}

extern "C" void kernel_launch(void* const* d_in, const int* in_sizes, int n_in,
                              void* d_out, int out_size, void* d_ws, size_t ws_size,
                              hipStream_t stream) {
    const void* x   = d_in[0];
    const int* ei   = (const int*)d_in[1];
    const void* Wl0 = d_in[3];  const void* bl0 = d_in[4];
    const void* Wr0 = d_in[5];  const void* br0 = d_in[6];
    const void* at0 = d_in[7];  const void* b0  = d_in[8];
    const void* Wl1 = d_in[9];  const void* bl1 = d_in[10];
    const void* Wr1 = d_in[11]; const void* br1 = d_in[12];
    const void* at1 = d_in[13]; const void* b1  = d_in[14];
    const void* Wl2 = d_in[15]; const void* bl2 = d_in[16];
    const void* Wr2 = d_in[17]; const void* br2 = d_in[18];
    const void* at2 = d_in[19]; const void* b2  = d_in[20];
    const void* Wro = d_in[21]; const void* bro = d_in[22];

    const int* srcArr = ei;
    const int* dstArr = ei + EE;

    float* wf = (float*)d_ws;
    float* WT0   = wf;                        // 16384
    float* WT1   = wf + 16384;                // 8192
    float* WT2   = wf + 24576;                // 8192
    float* small = wf + 32768;                // 1536
    int*   flag  = (int*)(wf + 34304);        // pad 64
    int*   rowptr = (int*)(wf + 34368);       // 80001 (pad 80128)
    int*   bsums  = (int*)(wf + 114496);      // 512
    int*   fillc  = (int*)(wf + 115008);      // 80000 (per-dst counts)
    int*   bucket_cnt  = (int*)(wf + 195008); // 128
    int*   bucket_base = (int*)(wf + 195136); // 128 (+1 used)
    int*   chunkcnt    = (int*)(wf + 195264); // NBUK*NCH = 49375 (pad 49472)
    int2*  part   = (int2*)(wf + 244736);     // EE int2 = 2560000 ints
    int2*  col2   = (int2*)(wf + 2804736);    // 2560000
    int2*  sq     = (int2*)(wf + 5364736);    // (EE+NN) int2 = 2720000 ints
    __half* xlh   = (__half*)(wf + 8084736);  // NN*64 halves = 2560000 floats
    float* xr = wf + 10644736;                // 5120000
    float* hA = xr + (size_t)NN * 64;         // 5120000

    float* biasLR0 = small;        float* biasLR1 = small + 128; float* biasLR2 = small + 256;
    float* attf0 = small + 384;    float* attf1 = small + 448;   float* attf2 = small + 512;
    float* bf0   = small + 576;    float* bf1   = small + 640;   float* bf2   = small + 704;
    float* WROf  = small + 768;    float* brof  = small + 1408;

    detect_kernel<<<dim3(1), dim3(64), 0, stream>>>((const unsigned*)Wl0, flag);

    preconvert<<<dim3(134), dim3(256), 0, stream>>>(
        Wl0, Wr0, Wl1, Wr1, Wl2, Wr2, bl0, br0, bl1, br1, bl2, br2,
        at0, at1, at2, b0, b1, b2, Wro, bro, WT0, WT1, WT2, small, flag);

    // deterministic edge sort
    chunkhist_kernel<<<dim3(NCH), dim3(256), 0, stream>>>(dstArr, chunkcnt);
    cscan_kernel<<<dim3(NBUK), dim3(1024), 0, stream>>>(chunkcnt, bucket_cnt);
    bscan_kernel<<<dim3(1), dim3(128), 0, stream>>>(bucket_cnt, bucket_base);
    part_kernel<<<dim3(NCH), dim3(256), 0, stream>>>(srcArr, dstArr, chunkcnt, bucket_base, part);
    hist_part_kernel<<<dim3(NBUK), dim3(256), 0, stream>>>(part, bucket_base, fillc);
    scan1<<<dim3(313), dim3(256), 0, stream>>>(fillc, rowptr, bsums);
    scan2<<<dim3(1), dim3(512), 0, stream>>>(bsums, 313);
    scan3<<<dim3(313), dim3(256), 0, stream>>>(rowptr, bsums);
    scatter2_kernel<<<dim3(NBUK), dim3(256), 0, stream>>>(part, bucket_base, rowptr, col2);

    const int SGRID = (ETOT + 255) / 256;

    // layer 0
    lin_fast<128, true><<<dim3(NN / 64), dim3(256), 0, stream>>>(x, WT0, biasLR0, xlh, xr, flag);
    score_kernel<<<dim3(SGRID), dim3(256), 0, stream>>>(xlh, xr, attf0, col2, sq);
    agg3_kernel<<<dim3(NN / 4), dim3(256), 0, stream>>>(xlh, bf0, rowptr, sq, hA);
    // layer 1
    lin_fast<64, false><<<dim3(NN / 64), dim3(256), 0, stream>>>(hA, WT1, biasLR1, xlh, xr, flag);
    score_kernel<<<dim3(SGRID), dim3(256), 0, stream>>>(xlh, xr, attf1, col2, sq);
    agg3_kernel<<<dim3(NN / 4), dim3(256), 0, stream>>>(xlh, bf1, rowptr, sq, hA);
    // layer 2
    lin_fast<64, false><<<dim3(NN / 64), dim3(256), 0, stream>>>(hA, WT2, biasLR2, xlh, xr, flag);
    score_kernel<<<dim3(SGRID), dim3(256), 0, stream>>>(xlh, xr, attf2, col2, sq);
    agg3_kernel<<<dim3(NN / 4), dim3(256), 0, stream>>>(xlh, bf2, rowptr, sq, hA);

    // readout (thread-per-node serial dot)
    readout2_kernel<<<dim3(313), dim3(256), 0, stream>>>(hA, WROf, brof, d_out, flag);
}

// Round 13
// 442.838 us; speedup vs baseline: 1.4022x; 1.2437x over previous
//
#include <hip/hip_runtime.h>
#include <hip/hip_bf16.h>
#include <hip/hip_fp16.h>

// GATv2 3-layer, N=80000 E=1280000 FIN=128 H=64 OUT=10. fp32 compute.
// Round 13: score fused into agg (agg4): the 8-rows-per-gather layout puts
// edge e's full xl row in one 8-lane octet, so the att-dot is a 3-stage
// intra-octet butterfly on register data. Kills 3 score dispatches + sq
// buffer + half of the edge-phase xl gather bytes.

#define NN 80000
#define EE 1280000
#define FIN 128
#define HH 64
#define OUTD 10
#define NBUK 79            // dst>>10 buckets (79*1024 >= 80000)
#define PCH 2048           // edges per partition chunk
#define NCH 625            // EE / PCH

typedef __hip_bfloat16 bf16;

__device__ __forceinline__ float ldw(const void* p, int i, int f) {
    return f ? __bfloat162float(((const bf16*)p)[i]) : ((const float*)p)[i];
}

// ---------------- dtype detect ----------------
__global__ void detect_kernel(const unsigned* __restrict__ w, int* __restrict__ flag) {
    int lane = threadIdx.x;
    int big = 0;
    for (int i = lane; i < 2048; i += 64) {
        unsigned u = w[i];
        float a = __uint_as_float(u << 16);
        float b = __uint_as_float(u & 0xffff0000u);
        if (!(fabsf(a) <= 1024.f)) big = 1;
        if (!(fabsf(b) <= 1024.f)) big = 1;
    }
    big = (__ballot(big) != 0ull) ? 1 : 0;
    if (lane == 0) flag[0] = big ? 0 : 1;     // 1 = bf16 storage, 0 = fp32
}

// ---------------- preconvert weights: WT[k*128 + j] ----------------
__global__ void preconvert(
    const void* Wl0, const void* Wr0, const void* Wl1, const void* Wr1,
    const void* Wl2, const void* Wr2,
    const void* bl0, const void* br0, const void* bl1, const void* br1,
    const void* bl2, const void* br2,
    const void* att0, const void* att1, const void* att2,
    const void* b0, const void* b1, const void* b2,
    const void* Wro, const void* bro,
    float* WT0, float* WT1, float* WT2, float* small,
    const int* __restrict__ flagp)
{
    const int f = flagp[0];
    int t = blockIdx.x * 256 + threadIdx.x;
    if (t < 16384) {
        int j = t & 127, k = t >> 7;
        float v = (j < 64) ? ldw(Wl0, j * 128 + k, f) : ldw(Wr0, (j - 64) * 128 + k, f);
        WT0[k * 128 + j] = v;
    } else if (t < 24576) {
        int u = t - 16384; int j = u & 127, k = u >> 7;
        float v = (j < 64) ? ldw(Wl1, j * 64 + k, f) : ldw(Wr1, (j - 64) * 64 + k, f);
        WT1[k * 128 + j] = v;
    } else if (t < 32768) {
        int u = t - 24576; int j = u & 127, k = u >> 7;
        float v = (j < 64) ? ldw(Wl2, j * 64 + k, f) : ldw(Wr2, (j - 64) * 64 + k, f);
        WT2[k * 128 + j] = v;
    } else if (t < 34304) {
        int s = t - 32768;
        const void* BL[3] = { bl0, bl1, bl2 };
        const void* BR[3] = { br0, br1, br2 };
        const void* AT[3] = { att0, att1, att2 };
        const void* BB[3] = { b0, b1, b2 };
        float v = 0.f;
        if (s < 384) {
            int l = s / 128, r = s % 128;
            v = (r < 64) ? ldw(BL[l], r, f) : ldw(BR[l], r - 64, f);
        } else if (s < 576) {
            int q = s - 384; v = ldw(AT[q / 64], q % 64, f);
        } else if (s < 768) {
            int q = s - 576; v = ldw(BB[q / 64], q % 64, f);
        } else if (s < 1408) {
            v = ldw(Wro, s - 768, f);
        } else if (s < 1418) {
            v = ldw(bro, s - 1408, f);
        } else return;
        small[s] = v;
    }
}

// ---------------- A: per-chunk bucket histogram ----------------
__global__ __launch_bounds__(256) void chunkhist_kernel(const int* __restrict__ dst,
                                                        int* __restrict__ chunkcnt)
{
    __shared__ int h[NBUK];
    const int tid = threadIdx.x, c = blockIdx.x;
    for (int i = tid; i < NBUK; i += 256) h[i] = 0;
    __syncthreads();
    const int e0 = c * PCH + tid * 8;
    int4 a = *(const int4*)(dst + e0);
    int4 b = *(const int4*)(dst + e0 + 4);
    atomicAdd(&h[a.x >> 10], 1); atomicAdd(&h[a.y >> 10], 1);
    atomicAdd(&h[a.z >> 10], 1); atomicAdd(&h[a.w >> 10], 1);
    atomicAdd(&h[b.x >> 10], 1); atomicAdd(&h[b.y >> 10], 1);
    atomicAdd(&h[b.z >> 10], 1); atomicAdd(&h[b.w >> 10], 1);
    __syncthreads();
    for (int i = tid; i < NBUK; i += 256) chunkcnt[i * NCH + c] = h[i];
}

// ---------------- B1: per-bucket exclusive scan over chunk counts ----------
__global__ __launch_bounds__(1024) void cscan_kernel(int* __restrict__ chunkcnt,
                                                     int* __restrict__ bucket_cnt)
{
    __shared__ int s[1024];
    const int b = blockIdx.x, t = threadIdx.x;
    int v = (t < NCH) ? chunkcnt[b * NCH + t] : 0;
    s[t] = v;
    __syncthreads();
    #pragma unroll
    for (int off = 1; off < 1024; off <<= 1) {
        int u = (t >= off) ? s[t - off] : 0;
        __syncthreads();
        s[t] += u;
        __syncthreads();
    }
    if (t < NCH) chunkcnt[b * NCH + t] = s[t] - v;
    if (t == NCH - 1) bucket_cnt[b] = s[t];
}

// ---------------- B2: scan buckets -> bucket_base ----------------
__global__ void bscan_kernel(const int* __restrict__ bucket_cnt,
                             int* __restrict__ bucket_base)
{
    __shared__ int sc[128];
    const int t = threadIdx.x;
    sc[t] = (t < NBUK) ? bucket_cnt[t] : 0;
    __syncthreads();
    #pragma unroll
    for (int off = 1; off < 128; off <<= 1) {
        int v = (t >= off) ? sc[t - off] : 0;
        __syncthreads();
        sc[t] += v;
        __syncthreads();
    }
    if (t < NBUK) bucket_base[t] = (t == 0) ? 0 : sc[t - 1];
    if (t == 0) bucket_base[NBUK] = sc[NBUK - 1];
}

// ---------------- C: deterministic partition into buckets -------------------
__global__ __launch_bounds__(256) void part_kernel(const int* __restrict__ src,
                                                   const int* __restrict__ dst,
                                                   const int* __restrict__ chunkcnt,
                                                   const int* __restrict__ bucket_base,
                                                   int2* __restrict__ part)
{
    __shared__ int hcnt[NBUK];
    __shared__ int sc[128];
    __shared__ int hbase[NBUK + 1];
    __shared__ int hpos[NBUK];
    __shared__ int hgb[NBUK];
    __shared__ int2 stage[PCH];
    const int tid = threadIdx.x, c = blockIdx.x;

    for (int i = tid; i < NBUK; i += 256) hcnt[i] = 0;
    __syncthreads();

    const int e0 = c * PCH + tid * 8;
    int4 sa = *(const int4*)(src + e0);
    int4 sb = *(const int4*)(src + e0 + 4);
    int4 da = *(const int4*)(dst + e0);
    int4 db = *(const int4*)(dst + e0 + 4);
    int dv[8] = { da.x, da.y, da.z, da.w, db.x, db.y, db.z, db.w };
    int sv[8] = { sa.x, sa.y, sa.z, sa.w, sb.x, sb.y, sb.z, sb.w };
    #pragma unroll
    for (int u = 0; u < 8; u++) atomicAdd(&hcnt[dv[u] >> 10], 1);
    __syncthreads();

    if (tid < 128) sc[tid] = (tid < NBUK) ? hcnt[tid] : 0;
    __syncthreads();
    #pragma unroll
    for (int off = 1; off < 128; off <<= 1) {
        int v = (tid < 128 && tid >= off) ? sc[tid - off] : 0;
        __syncthreads();
        if (tid < 128) sc[tid] += v;
        __syncthreads();
    }
    if (tid < NBUK) {
        int b = (tid == 0) ? 0 : sc[tid - 1];
        hbase[tid] = b;
        hpos[tid] = b;
        hgb[tid] = bucket_base[tid] + chunkcnt[tid * NCH + c];
    }
    if (tid == 0) hbase[NBUK] = PCH;
    __syncthreads();

    #pragma unroll
    for (int u = 0; u < 8; u++) {
        int p = atomicAdd(&hpos[dv[u] >> 10], 1);
        stage[p] = make_int2(sv[u], dv[u]);
    }
    __syncthreads();

    for (int s = tid; s < PCH; s += 256) {
        int lo = 0, hi = NBUK;
        #pragma unroll
        for (int it = 0; it < 7; it++) {
            int mid = (lo + hi) >> 1;
            if (hbase[mid] <= s) lo = mid; else hi = mid;
        }
        part[hgb[lo] + (s - hbase[lo])] = stage[s];
    }
}

// ---------------- fine hist: one block per bucket, LDS counters -------------
__global__ __launch_bounds__(256) void hist_part_kernel(const int2* __restrict__ part,
                                                        const int* __restrict__ bucket_base,
                                                        int* __restrict__ cnt)
{
    __shared__ int lcnt[1024];
    const int b = blockIdx.x, tid = threadIdx.x;
    const int dbase = b << 10;
    for (int i = tid; i < 1024; i += 256) lcnt[i] = 0;
    __syncthreads();
    const int eb = bucket_base[b], ee = bucket_base[b + 1];
    for (int e = eb + tid; e < ee; e += 256)
        atomicAdd(&lcnt[part[e].y - dbase], 1);
    __syncthreads();
    const int nd = min(1024, NN - dbase);
    for (int i = tid; i < nd; i += 256) cnt[dbase + i] = lcnt[i];
}

// ---------------- scans ----------------
__global__ void scan1(const int* __restrict__ cnt, int* __restrict__ rowptr,
                      int* __restrict__ bsums) {
    __shared__ int sh[256];
    int i = blockIdx.x * 256 + threadIdx.x;
    int tid = threadIdx.x;
    int c = (i < NN) ? cnt[i] : 0;
    sh[tid] = c;
    __syncthreads();
    #pragma unroll
    for (int off = 1; off < 256; off <<= 1) {
        int t = (tid >= off) ? sh[tid - off] : 0;
        __syncthreads();
        sh[tid] += t;
        __syncthreads();
    }
    if (i < NN) rowptr[i + 1] = sh[tid];
    if (tid == 255) bsums[blockIdx.x] = sh[255];
}

__global__ void scan2(int* __restrict__ bsums, int nb) {
    __shared__ int sh[512];
    int t = threadIdx.x;
    sh[t] = (t < nb) ? bsums[t] : 0;
    __syncthreads();
    #pragma unroll
    for (int off = 1; off < 512; off <<= 1) {
        int v = (t >= off) ? sh[t - off] : 0;
        __syncthreads();
        sh[t] += v;
        __syncthreads();
    }
    if (t < nb) bsums[t] = sh[t];
}

__global__ void scan3(int* __restrict__ rowptr, const int* __restrict__ bsums) {
    int i = blockIdx.x * 256 + threadIdx.x;
    if (i == 0) rowptr[0] = 0;
    int add = (blockIdx.x == 0) ? 0 : bsums[blockIdx.x - 1];
    if (i < NN) rowptr[i + 1] += add;
}

// ---------------- P2: fine scatter, one block per bucket --------------------
__global__ __launch_bounds__(256) void scatter2_kernel(const int2* __restrict__ part,
                                                       const int* __restrict__ bucket_base,
                                                       const int* __restrict__ rowptr,
                                                       int2* __restrict__ col2)
{
    __shared__ int lfill[1024];
    const int b = blockIdx.x, tid = threadIdx.x;
    const int dbase = b << 10;
    const int nd = min(1024, NN - dbase);
    for (int i = tid; i < nd; i += 256) lfill[i] = rowptr[dbase + i];
    __syncthreads();
    const int eb = bucket_base[b], ee = bucket_base[b + 1];
    for (int e = eb + tid; e < ee; e += 256) {
        int2 sd = part[e];
        int pos = atomicAdd(&lfill[sd.y - dbase], 1);
        col2[pos] = sd;
    }
}

// ---------------- linear: xl (fp16) | xr (fp32) ----------------
template<int F, bool L0>
__global__ __launch_bounds__(256) void lin_fast(const void* __restrict__ hin_,
                                                const float* __restrict__ WT,
                                                const float* __restrict__ biasLR,
                                                __half* __restrict__ xlh,
                                                float* __restrict__ xr,
                                                const int* __restrict__ flagp)
{
    constexpr int LDR = 72;
    __shared__ __align__(16) float xs[F * LDR];
    const int t = threadIdx.x;
    const int nb = blockIdx.x * 64;

    if (L0 && flagp[0]) {
        const unsigned* hp = (const unsigned*)hin_;
        for (int idx = t; idx < 64 * (F / 2); idx += 256) {
            int r = idx / (F / 2), c = idx % (F / 2);
            unsigned u = hp[(size_t)(nb + r) * (F / 2) + c];
            xs[(2 * c) * LDR + r]     = __uint_as_float(u << 16);
            xs[(2 * c + 1) * LDR + r] = __uint_as_float(u & 0xffff0000u);
        }
    } else {
        const float* hp = (const float*)hin_;
        for (int idx = t; idx < 64 * F; idx += 256) {
            int r = idx / F, c = idx % F;
            xs[c * LDR + r] = hp[(size_t)(nb + r) * F + c];
        }
    }
    __syncthreads();

    const int c = t & 31;
    const int g = t >> 5;
    const float4* W4 = (const float4*)WT;
    const float4 bias = ((const float4*)biasLR)[c];
    float4 acc[8];
    #pragma unroll
    for (int u = 0; u < 8; u++) acc[u] = bias;

    #pragma unroll 2
    for (int k = 0; k < F; k++) {
        float4 w  = W4[k * 32 + c];
        float4 xa = *(const float4*)&xs[k * LDR + g * 8];
        float4 xb = *(const float4*)&xs[k * LDR + g * 8 + 4];
        acc[0].x = fmaf(xa.x, w.x, acc[0].x); acc[0].y = fmaf(xa.x, w.y, acc[0].y);
        acc[0].z = fmaf(xa.x, w.z, acc[0].z); acc[0].w = fmaf(xa.x, w.w, acc[0].w);
        acc[1].x = fmaf(xa.y, w.x, acc[1].x); acc[1].y = fmaf(xa.y, w.y, acc[1].y);
        acc[1].z = fmaf(xa.y, w.z, acc[1].z); acc[1].w = fmaf(xa.y, w.w, acc[1].w);
        acc[2].x = fmaf(xa.z, w.x, acc[2].x); acc[2].y = fmaf(xa.z, w.y, acc[2].y);
        acc[2].z = fmaf(xa.z, w.z, acc[2].z); acc[2].w = fmaf(xa.z, w.w, acc[2].w);
        acc[3].x = fmaf(xa.w, w.x, acc[3].x); acc[3].y = fmaf(xa.w, w.y, acc[3].y);
        acc[3].z = fmaf(xa.w, w.z, acc[3].z); acc[3].w = fmaf(xa.w, w.w, acc[3].w);
        acc[4].x = fmaf(xb.x, w.x, acc[4].x); acc[4].y = fmaf(xb.x, w.y, acc[4].y);
        acc[4].z = fmaf(xb.x, w.z, acc[4].z); acc[4].w = fmaf(xb.x, w.w, acc[4].w);
        acc[5].x = fmaf(xb.y, w.x, acc[5].x); acc[5].y = fmaf(xb.y, w.y, acc[5].y);
        acc[5].z = fmaf(xb.y, w.z, acc[5].z); acc[5].w = fmaf(xb.y, w.w, acc[5].w);
        acc[6].x = fmaf(xb.z, w.x, acc[6].x); acc[6].y = fmaf(xb.z, w.y, acc[6].y);
        acc[6].z = fmaf(xb.z, w.z, acc[6].z); acc[6].w = fmaf(xb.z, w.w, acc[6].w);
        acc[7].x = fmaf(xb.w, w.x, acc[7].x); acc[7].y = fmaf(xb.w, w.y, acc[7].y);
        acc[7].z = fmaf(xb.w, w.z, acc[7].z); acc[7].w = fmaf(xb.w, w.w, acc[7].w);
    }

    const int j0 = 4 * c;
    if (j0 < 64) {
        #pragma unroll
        for (int u = 0; u < 8; u++) {
            size_t row = nb + g * 8 + u;
            __half* xp = xlh + row * 64 + j0;
            *(__half2*)(xp)     = __floats2half2_rn(acc[u].x, acc[u].y);
            *(__half2*)(xp + 2) = __floats2half2_rn(acc[u].z, acc[u].w);
        }
    } else {
        #pragma unroll
        for (int u = 0; u < 8; u++) {
            size_t row = nb + g * 8 + u;
            *(float4*)(xr + row * 64 + (j0 - 64)) = acc[u];
        }
    }
}

// ---------------- fused score+aggregate: wave/node, 8 rows per gather -------
#define DECODE8(U, D) { \
    float2 _f0 = __half22float2(*(__half2*)&U.x); \
    float2 _f1 = __half22float2(*(__half2*)&U.y); \
    float2 _f2 = __half22float2(*(__half2*)&U.z); \
    float2 _f3 = __half22float2(*(__half2*)&U.w); \
    D[0]=_f0.x; D[1]=_f0.y; D[2]=_f1.x; D[3]=_f1.y; \
    D[4]=_f2.x; D[5]=_f2.y; D[6]=_f3.x; D[7]=_f3.y; }

__global__ __launch_bounds__(256) void agg4_kernel(const __half* __restrict__ xlh,
                                                   const float* __restrict__ xr,
                                                   const float* __restrict__ attf,
                                                   const float* __restrict__ bf,
                                                   const int* __restrict__ rowptr,
                                                   const int2* __restrict__ col2,
                                                   float* __restrict__ hout)
{
    const int lane = threadIdx.x & 63;
    const int g = lane >> 3;        // subgroup -> edge slot
    const int r = lane & 7;         // feature octet
    int iw = blockIdx.x * 4 + (threadIdx.x >> 6);
    if (iw >= NN) return;
    const int i = __builtin_amdgcn_readfirstlane(iw);

    float xri[8], att[8];
    {
        float4 xa = *(const float4*)(xr + (size_t)i * 64 + r * 8);
        float4 xb = *(const float4*)(xr + (size_t)i * 64 + r * 8 + 4);
        xri[0]=xa.x; xri[1]=xa.y; xri[2]=xa.z; xri[3]=xa.w;
        xri[4]=xb.x; xri[5]=xb.y; xri[6]=xb.z; xri[7]=xb.w;
        float4 aa = *(const float4*)(attf + r * 8);
        float4 ab = *(const float4*)(attf + r * 8 + 4);
        att[0]=aa.x; att[1]=aa.y; att[2]=aa.z; att[3]=aa.w;
        att[4]=ab.x; att[5]=ab.y; att[6]=ab.z; att[7]=ab.w;
    }

    // self edge: scored inline
    uint4 srow = *(const uint4*)(xlh + (size_t)i * 64 + r * 8);
    float s[8]; DECODE8(srow, s);
    float ps = 0.f;
    #pragma unroll
    for (int k = 0; k < 8; k++) {
        float u = s[k] + xri[k];
        ps = fmaf(att[k], fmaf(0.4f, fabsf(u), 0.6f * u), ps);
    }
    ps += __shfl_xor(ps, 1, 64);
    ps += __shfl_xor(ps, 2, 64);
    ps += __shfl_xor(ps, 4, 64);
    float wself = __expf(fminf(ps, 60.f));

    float acc[8];
    float denom;
    if (g == 0) {
        #pragma unroll
        for (int k = 0; k < 8; k++) acc[k] = wself * s[k];
        denom = wself;
    } else {
        #pragma unroll
        for (int k = 0; k < 8; k++) acc[k] = 0.f;
        denom = 0.f;
    }

    const int e0 = rowptr[i], e1 = rowptr[i + 1];
    const int n = e1 - e0;
    const int eL = e1 - 1;

    for (int base = 0; base < n; base += 16) {
        const int j = e0 + base;
        int sa = col2[min(j + g, eL)].x;
        int sb = col2[min(j + 8 + g, eL)].x;
        uint4 ua = *(const uint4*)(xlh + (size_t)sa * 64 + r * 8);
        uint4 ub = *(const uint4*)(xlh + (size_t)sb * 64 + r * 8);
        float A[8], B[8];
        DECODE8(ua, A);
        DECODE8(ub, B);

        float pa = 0.f, pb = 0.f;
        #pragma unroll
        for (int k = 0; k < 8; k++) {
            float va = A[k] + xri[k];
            float vb = B[k] + xri[k];
            pa = fmaf(att[k], fmaf(0.4f, fabsf(va), 0.6f * va), pa);
            pb = fmaf(att[k], fmaf(0.4f, fabsf(vb), 0.6f * vb), pb);
        }
        pa += __shfl_xor(pa, 1, 64);  pb += __shfl_xor(pb, 1, 64);
        pa += __shfl_xor(pa, 2, 64);  pb += __shfl_xor(pb, 2, 64);
        pa += __shfl_xor(pa, 4, 64);  pb += __shfl_xor(pb, 4, 64);

        float wa = (base + g < n)     ? __expf(fminf(pa, 60.f)) : 0.f;
        float wb = (base + 8 + g < n) ? __expf(fminf(pb, 60.f)) : 0.f;

        #pragma unroll
        for (int k = 0; k < 8; k++) {
            acc[k] = fmaf(wa, A[k], acc[k]);
            acc[k] = fmaf(wb, B[k], acc[k]);
        }
        denom += wa + wb;
    }

    #pragma unroll
    for (int off = 8; off < 64; off <<= 1) {
        #pragma unroll
        for (int k = 0; k < 8; k++) acc[k] += __shfl_xor(acc[k], off, 64);
        denom += __shfl_xor(denom, off, 64);
    }

    if (g == 0) {
        float inv = 1.f / denom;
        float4 bfa = *(const float4*)(bf + r * 8);
        float4 bfb = *(const float4*)(bf + r * 8 + 4);
        float o0 = fmaxf(fmaf(acc[0], inv, bfa.x), 0.f);
        float o1 = fmaxf(fmaf(acc[1], inv, bfa.y), 0.f);
        float o2 = fmaxf(fmaf(acc[2], inv, bfa.z), 0.f);
        float o3 = fmaxf(fmaf(acc[3], inv, bfa.w), 0.f);
        float o4 = fmaxf(fmaf(acc[4], inv, bfb.x), 0.f);
        float o5 = fmaxf(fmaf(acc[5], inv, bfb.y), 0.f);
        float o6 = fmaxf(fmaf(acc[6], inv, bfb.z), 0.f);
        float o7 = fmaxf(fmaf(acc[7], inv, bfb.w), 0.f);
        float* op = hout + (size_t)i * 64 + r * 8;
        *(float4*)(op)     = make_float4(o0, o1, o2, o3);
        *(float4*)(op + 4) = make_float4(o4, o5, o6, o7);
    }
}

// ---------------- readout: thread-per-node serial dot, Wro^T in LDS --------
__global__ __launch_bounds__(256) void readout2_kernel(const float* __restrict__ h,
                                                       const float* __restrict__ WROf,
                                                       const float* __restrict__ brof,
                                                       void* __restrict__ out,
                                                       const int* __restrict__ flagp)
{
    __shared__ float wsh[640];   // wsh[k*10+o] = Wro[o][k]
    __shared__ float bsh[OUTD];
    const int tid = threadIdx.x;
    for (int idx = tid; idx < 640; idx += 256) {
        int k = idx / 10, o = idx % 10;
        wsh[idx] = WROf[o * 64 + k];
    }
    if (tid < OUTD) bsh[tid] = brof[tid];
    __syncthreads();

    const int i = blockIdx.x * 256 + tid;
    if (i >= NN) return;
    const int f = flagp[0];

    float res[OUTD];
    #pragma unroll
    for (int o = 0; o < OUTD; o++) res[o] = bsh[o];

    const float4* h4 = (const float4*)(h + (size_t)i * 64);
    #pragma unroll 4
    for (int c = 0; c < 16; c++) {
        float4 hv = h4[c];
        const float* wp = &wsh[c * 40];
        #pragma unroll
        for (int o = 0; o < OUTD; o++) {
            float t = fmaf(hv.x, wp[o], fmaf(hv.y, wp[10 + o],
                      fmaf(hv.z, wp[20 + o], hv.w * wp[30 + o])));
            res[o] += t;
        }
    }

    if (f) {
        bf16* op = (bf16*)out + (size_t)i * OUTD;
        #pragma unroll
        for (int o = 0; o < OUTD; o++) op[o] = __float2bfloat16(res[o]);
    } else {
        float* op = (float*)out + (size_t)i * OUTD;
        #pragma unroll
        for (int o = 0; o < OUTD; o++) op[o] = res[o];
    }
}

extern "C" void kernel_launch(void* const* d_in, const int* in_sizes, int n_in,
                              void* d_out, int out_size, void* d_ws, size_t ws_size,
                              hipStream_t stream) {
    const void* x   = d_in[0];
    const int* ei   = (const int*)d_in[1];
    const void* Wl0 = d_in[3];  const void* bl0 = d_in[4];
    const void* Wr0 = d_in[5];  const void* br0 = d_in[6];
    const void* at0 = d_in[7];  const void* b0  = d_in[8];
    const void* Wl1 = d_in[9];  const void* bl1 = d_in[10];
    const void* Wr1 = d_in[11]; const void* br1 = d_in[12];
    const void* at1 = d_in[13]; const void* b1  = d_in[14];
    const void* Wl2 = d_in[15]; const void* bl2 = d_in[16];
    const void* Wr2 = d_in[17]; const void* br2 = d_in[18];
    const void* at2 = d_in[19]; const void* b2  = d_in[20];
    const void* Wro = d_in[21]; const void* bro = d_in[22];

    const int* srcArr = ei;
    const int* dstArr = ei + EE;

    float* wf = (float*)d_ws;
    float* WT0   = wf;                        // 16384
    float* WT1   = wf + 16384;                // 8192
    float* WT2   = wf + 24576;                // 8192
    float* small = wf + 32768;                // 1536
    int*   flag  = (int*)(wf + 34304);        // pad 64
    int*   rowptr = (int*)(wf + 34368);       // 80001 (pad 80128)
    int*   bsums  = (int*)(wf + 114496);      // 512
    int*   fillc  = (int*)(wf + 115008);      // 80000 (per-dst counts)
    int*   bucket_cnt  = (int*)(wf + 195008); // 128
    int*   bucket_base = (int*)(wf + 195136); // 128 (+1 used)
    int*   chunkcnt    = (int*)(wf + 195264); // NBUK*NCH = 49375 (pad 49472)
    int2*  part   = (int2*)(wf + 244736);     // EE int2 = 2560000 ints
    int2*  col2   = (int2*)(wf + 2804736);    // 2560000
    __half* xlh   = (__half*)(wf + 5364736);  // NN*64 halves = 2560000 floats
    float* xr = wf + 7924736;                 // 5120000
    float* hA = xr + (size_t)NN * 64;         // 5120000

    float* biasLR0 = small;        float* biasLR1 = small + 128; float* biasLR2 = small + 256;
    float* attf0 = small + 384;    float* attf1 = small + 448;   float* attf2 = small + 512;
    float* bf0   = small + 576;    float* bf1   = small + 640;   float* bf2   = small + 704;
    float* WROf  = small + 768;    float* brof  = small + 1408;

    detect_kernel<<<dim3(1), dim3(64), 0, stream>>>((const unsigned*)Wl0, flag);

    preconvert<<<dim3(134), dim3(256), 0, stream>>>(
        Wl0, Wr0, Wl1, Wr1, Wl2, Wr2, bl0, br0, bl1, br1, bl2, br2,
        at0, at1, at2, b0, b1, b2, Wro, bro, WT0, WT1, WT2, small, flag);

    // deterministic edge sort
    chunkhist_kernel<<<dim3(NCH), dim3(256), 0, stream>>>(dstArr, chunkcnt);
    cscan_kernel<<<dim3(NBUK), dim3(1024), 0, stream>>>(chunkcnt, bucket_cnt);
    bscan_kernel<<<dim3(1), dim3(128), 0, stream>>>(bucket_cnt, bucket_base);
    part_kernel<<<dim3(NCH), dim3(256), 0, stream>>>(srcArr, dstArr, chunkcnt, bucket_base, part);
    hist_part_kernel<<<dim3(NBUK), dim3(256), 0, stream>>>(part, bucket_base, fillc);
    scan1<<<dim3(313), dim3(256), 0, stream>>>(fillc, rowptr, bsums);
    scan2<<<dim3(1), dim3(512), 0, stream>>>(bsums, 313);
    scan3<<<dim3(313), dim3(256), 0, stream>>>(rowptr, bsums);
    scatter2_kernel<<<dim3(NBUK), dim3(256), 0, stream>>>(part, bucket_base, rowptr, col2);

    // layer 0
    lin_fast<128, true><<<dim3(NN / 64), dim3(256), 0, stream>>>(x, WT0, biasLR0, xlh, xr, flag);
    agg4_kernel<<<dim3(NN / 4), dim3(256), 0, stream>>>(xlh, xr, attf0, bf0, rowptr, col2, hA);
    // layer 1
    lin_fast<64, false><<<dim3(NN / 64), dim3(256), 0, stream>>>(hA, WT1, biasLR1, xlh, xr, flag);
    agg4_kernel<<<dim3(NN / 4), dim3(256), 0, stream>>>(xlh, xr, attf1, bf1, rowptr, col2, hA);
    // layer 2
    lin_fast<64, false><<<dim3(NN / 64), dim3(256), 0, stream>>>(hA, WT2, biasLR2, xlh, xr, flag);
    agg4_kernel<<<dim3(NN / 4), dim3(256), 0, stream>>>(xlh, xr, attf2, bf2, rowptr, col2, hA);

    // readout (thread-per-node serial dot)
    readout2_kernel<<<dim3(313), dim3(256), 0, stream>>>(hA, WROf, brof, d_out, flag);
}

// Round 14
// 410.770 us; speedup vs baseline: 1.5117x; 1.0781x over previous
//
#include <hip/hip_runtime.h>
#include <hip/hip_bf16.h>
#include <hip/hip_fp16.h>

// GATv2 3-layer, N=80000 E=1280000 FIN=128 H=64 OUT=10.
// Round 14: lin rewritten on MFMA f16 (v_mfma_f32_16x16x32_f16):
//   A = h tile (64xF fp16, XOR-swizzled LDS), B = W fp16 [j][k] (L1-hot),
//   bias seeded in acc, epilogue via padded LDS -> vector stores.
//   Was: fp32 VALU GEMM, 57us/dispatch regardless of F (fixed-cost-bound).
// agg4 (fused score+aggregate), CSR partition, readout2 unchanged.

#define NN 80000
#define EE 1280000
#define FIN 128
#define HH 64
#define OUTD 10
#define NBUK 79            // dst>>10 buckets (79*1024 >= 80000)
#define PCH 2048           // edges per partition chunk
#define NCH 625            // EE / PCH

typedef __hip_bfloat16 bf16;
typedef _Float16 f16x8 __attribute__((ext_vector_type(8)));
typedef float f32x4 __attribute__((ext_vector_type(4)));

__device__ __forceinline__ float ldw(const void* p, int i, int f) {
    return f ? __bfloat162float(((const bf16*)p)[i]) : ((const float*)p)[i];
}

// ---------------- dtype detect ----------------
__global__ void detect_kernel(const unsigned* __restrict__ w, int* __restrict__ flag) {
    int lane = threadIdx.x;
    int big = 0;
    for (int i = lane; i < 2048; i += 64) {
        unsigned u = w[i];
        float a = __uint_as_float(u << 16);
        float b = __uint_as_float(u & 0xffff0000u);
        if (!(fabsf(a) <= 1024.f)) big = 1;
        if (!(fabsf(b) <= 1024.f)) big = 1;
    }
    big = (__ballot(big) != 0ull) ? 1 : 0;
    if (lane == 0) flag[0] = big ? 0 : 1;     // 1 = bf16 storage, 0 = fp32
}

// ---------------- preconvert weights: Wh[j*F + k] fp16 ([j][k] = B-operand) --
__global__ void preconvert(
    const void* Wl0, const void* Wr0, const void* Wl1, const void* Wr1,
    const void* Wl2, const void* Wr2,
    const void* bl0, const void* br0, const void* bl1, const void* br1,
    const void* bl2, const void* br2,
    const void* att0, const void* att1, const void* att2,
    const void* b0, const void* b1, const void* b2,
    const void* Wro, const void* bro,
    __half* Wh0, __half* Wh1, __half* Wh2, float* small,
    const int* __restrict__ flagp)
{
    const int f = flagp[0];
    int t = blockIdx.x * 256 + threadIdx.x;
    if (t < 16384) {                        // L0: j<128, k<128
        int j = t & 127, k = t >> 7;
        float v = (j < 64) ? ldw(Wl0, j * 128 + k, f) : ldw(Wr0, (j - 64) * 128 + k, f);
        Wh0[j * 128 + k] = __float2half(v);
    } else if (t < 24576) {                 // L1: j<128, k<64
        int u = t - 16384; int j = u & 127, k = u >> 7;
        float v = (j < 64) ? ldw(Wl1, j * 64 + k, f) : ldw(Wr1, (j - 64) * 64 + k, f);
        Wh1[j * 64 + k] = __float2half(v);
    } else if (t < 32768) {                 // L2
        int u = t - 24576; int j = u & 127, k = u >> 7;
        float v = (j < 64) ? ldw(Wl2, j * 64 + k, f) : ldw(Wr2, (j - 64) * 64 + k, f);
        Wh2[j * 64 + k] = __float2half(v);
    } else if (t < 34304) {
        int s = t - 32768;
        const void* BL[3] = { bl0, bl1, bl2 };
        const void* BR[3] = { br0, br1, br2 };
        const void* AT[3] = { att0, att1, att2 };
        const void* BB[3] = { b0, b1, b2 };
        float v = 0.f;
        if (s < 384) {
            int l = s / 128, r = s % 128;
            v = (r < 64) ? ldw(BL[l], r, f) : ldw(BR[l], r - 64, f);
        } else if (s < 576) {
            int q = s - 384; v = ldw(AT[q / 64], q % 64, f);
        } else if (s < 768) {
            int q = s - 576; v = ldw(BB[q / 64], q % 64, f);
        } else if (s < 1408) {
            v = ldw(Wro, s - 768, f);
        } else if (s < 1418) {
            v = ldw(bro, s - 1408, f);
        } else return;
        small[s] = v;
    }
}

// ---------------- A: per-chunk bucket histogram ----------------
__global__ __launch_bounds__(256) void chunkhist_kernel(const int* __restrict__ dst,
                                                        int* __restrict__ chunkcnt)
{
    __shared__ int h[NBUK];
    const int tid = threadIdx.x, c = blockIdx.x;
    for (int i = tid; i < NBUK; i += 256) h[i] = 0;
    __syncthreads();
    const int e0 = c * PCH + tid * 8;
    int4 a = *(const int4*)(dst + e0);
    int4 b = *(const int4*)(dst + e0 + 4);
    atomicAdd(&h[a.x >> 10], 1); atomicAdd(&h[a.y >> 10], 1);
    atomicAdd(&h[a.z >> 10], 1); atomicAdd(&h[a.w >> 10], 1);
    atomicAdd(&h[b.x >> 10], 1); atomicAdd(&h[b.y >> 10], 1);
    atomicAdd(&h[b.z >> 10], 1); atomicAdd(&h[b.w >> 10], 1);
    __syncthreads();
    for (int i = tid; i < NBUK; i += 256) chunkcnt[i * NCH + c] = h[i];
}

// ---------------- B1: per-bucket exclusive scan over chunk counts ----------
__global__ __launch_bounds__(1024) void cscan_kernel(int* __restrict__ chunkcnt,
                                                     int* __restrict__ bucket_cnt)
{
    __shared__ int s[1024];
    const int b = blockIdx.x, t = threadIdx.x;
    int v = (t < NCH) ? chunkcnt[b * NCH + t] : 0;
    s[t] = v;
    __syncthreads();
    #pragma unroll
    for (int off = 1; off < 1024; off <<= 1) {
        int u = (t >= off) ? s[t - off] : 0;
        __syncthreads();
        s[t] += u;
        __syncthreads();
    }
    if (t < NCH) chunkcnt[b * NCH + t] = s[t] - v;
    if (t == NCH - 1) bucket_cnt[b] = s[t];
}

// ---------------- B2: scan buckets -> bucket_base ----------------
__global__ void bscan_kernel(const int* __restrict__ bucket_cnt,
                             int* __restrict__ bucket_base)
{
    __shared__ int sc[128];
    const int t = threadIdx.x;
    sc[t] = (t < NBUK) ? bucket_cnt[t] : 0;
    __syncthreads();
    #pragma unroll
    for (int off = 1; off < 128; off <<= 1) {
        int v = (t >= off) ? sc[t - off] : 0;
        __syncthreads();
        sc[t] += v;
        __syncthreads();
    }
    if (t < NBUK) bucket_base[t] = (t == 0) ? 0 : sc[t - 1];
    if (t == 0) bucket_base[NBUK] = sc[NBUK - 1];
}

// ---------------- C: deterministic partition into buckets -------------------
__global__ __launch_bounds__(256) void part_kernel(const int* __restrict__ src,
                                                   const int* __restrict__ dst,
                                                   const int* __restrict__ chunkcnt,
                                                   const int* __restrict__ bucket_base,
                                                   int2* __restrict__ part)
{
    __shared__ int hcnt[NBUK];
    __shared__ int sc[128];
    __shared__ int hbase[NBUK + 1];
    __shared__ int hpos[NBUK];
    __shared__ int hgb[NBUK];
    __shared__ int2 stage[PCH];
    const int tid = threadIdx.x, c = blockIdx.x;

    for (int i = tid; i < NBUK; i += 256) hcnt[i] = 0;
    __syncthreads();

    const int e0 = c * PCH + tid * 8;
    int4 sa = *(const int4*)(src + e0);
    int4 sb = *(const int4*)(src + e0 + 4);
    int4 da = *(const int4*)(dst + e0);
    int4 db = *(const int4*)(dst + e0 + 4);
    int dv[8] = { da.x, da.y, da.z, da.w, db.x, db.y, db.z, db.w };
    int sv[8] = { sa.x, sa.y, sa.z, sa.w, sb.x, sb.y, sb.z, sb.w };
    #pragma unroll
    for (int u = 0; u < 8; u++) atomicAdd(&hcnt[dv[u] >> 10], 1);
    __syncthreads();

    if (tid < 128) sc[tid] = (tid < NBUK) ? hcnt[tid] : 0;
    __syncthreads();
    #pragma unroll
    for (int off = 1; off < 128; off <<= 1) {
        int v = (tid < 128 && tid >= off) ? sc[tid - off] : 0;
        __syncthreads();
        if (tid < 128) sc[tid] += v;
        __syncthreads();
    }
    if (tid < NBUK) {
        int b = (tid == 0) ? 0 : sc[tid - 1];
        hbase[tid] = b;
        hpos[tid] = b;
        hgb[tid] = bucket_base[tid] + chunkcnt[tid * NCH + c];
    }
    if (tid == 0) hbase[NBUK] = PCH;
    __syncthreads();

    #pragma unroll
    for (int u = 0; u < 8; u++) {
        int p = atomicAdd(&hpos[dv[u] >> 10], 1);
        stage[p] = make_int2(sv[u], dv[u]);
    }
    __syncthreads();

    for (int s = tid; s < PCH; s += 256) {
        int lo = 0, hi = NBUK;
        #pragma unroll
        for (int it = 0; it < 7; it++) {
            int mid = (lo + hi) >> 1;
            if (hbase[mid] <= s) lo = mid; else hi = mid;
        }
        part[hgb[lo] + (s - hbase[lo])] = stage[s];
    }
}

// ---------------- fine hist: one block per bucket, LDS counters -------------
__global__ __launch_bounds__(256) void hist_part_kernel(const int2* __restrict__ part,
                                                        const int* __restrict__ bucket_base,
                                                        int* __restrict__ cnt)
{
    __shared__ int lcnt[1024];
    const int b = blockIdx.x, tid = threadIdx.x;
    const int dbase = b << 10;
    for (int i = tid; i < 1024; i += 256) lcnt[i] = 0;
    __syncthreads();
    const int eb = bucket_base[b], ee = bucket_base[b + 1];
    for (int e = eb + tid; e < ee; e += 256)
        atomicAdd(&lcnt[part[e].y - dbase], 1);
    __syncthreads();
    const int nd = min(1024, NN - dbase);
    for (int i = tid; i < nd; i += 256) cnt[dbase + i] = lcnt[i];
}

// ---------------- scans ----------------
__global__ void scan1(const int* __restrict__ cnt, int* __restrict__ rowptr,
                      int* __restrict__ bsums) {
    __shared__ int sh[256];
    int i = blockIdx.x * 256 + threadIdx.x;
    int tid = threadIdx.x;
    int c = (i < NN) ? cnt[i] : 0;
    sh[tid] = c;
    __syncthreads();
    #pragma unroll
    for (int off = 1; off < 256; off <<= 1) {
        int t = (tid >= off) ? sh[tid - off] : 0;
        __syncthreads();
        sh[tid] += t;
        __syncthreads();
    }
    if (i < NN) rowptr[i + 1] = sh[tid];
    if (tid == 255) bsums[blockIdx.x] = sh[255];
}

__global__ void scan2(int* __restrict__ bsums, int nb) {
    __shared__ int sh[512];
    int t = threadIdx.x;
    sh[t] = (t < nb) ? bsums[t] : 0;
    __syncthreads();
    #pragma unroll
    for (int off = 1; off < 512; off <<= 1) {
        int v = (t >= off) ? sh[t - off] : 0;
        __syncthreads();
        sh[t] += v;
        __syncthreads();
    }
    if (t < nb) bsums[t] = sh[t];
}

__global__ void scan3(int* __restrict__ rowptr, const int* __restrict__ bsums) {
    int i = blockIdx.x * 256 + threadIdx.x;
    if (i == 0) rowptr[0] = 0;
    int add = (blockIdx.x == 0) ? 0 : bsums[blockIdx.x - 1];
    if (i < NN) rowptr[i + 1] += add;
}

// ---------------- P2: fine scatter, one block per bucket --------------------
__global__ __launch_bounds__(256) void scatter2_kernel(const int2* __restrict__ part,
                                                       const int* __restrict__ bucket_base,
                                                       const int* __restrict__ rowptr,
                                                       int2* __restrict__ col2)
{
    __shared__ int lfill[1024];
    const int b = blockIdx.x, tid = threadIdx.x;
    const int dbase = b << 10;
    const int nd = min(1024, NN - dbase);
    for (int i = tid; i < nd; i += 256) lfill[i] = rowptr[dbase + i];
    __syncthreads();
    const int eb = bucket_base[b], ee = bucket_base[b + 1];
    for (int e = eb + tid; e < ee; e += 256) {
        int2 sd = part[e];
        int pos = atomicAdd(&lfill[sd.y - dbase], 1);
        col2[pos] = sd;
    }
}

// ---------------- linear via MFMA f16: [64 x F] @ [F x 128] -----------------
// A staged fp16 in LDS, XOR-swizzled (octet ^= row&7). B = Wh[j][k] from L1.
// C/D: col=lane&15, row=(lane>>4)*4+reg; A: [m=lane&15][k=quad*8+j];
// B: [n=lane&15][k=quad*8+j] (k-major per lane).
#define ELX_S 72           // epilogue xl row stride (fp16)
#define EXR_S 68           // epilogue xr row stride (fp32)
template<int F, bool L0>
__global__ __launch_bounds__(256) void lin_mfma(const void* __restrict__ hin_,
                                                const __half* __restrict__ Wh,
                                                const float* __restrict__ biasLR,
                                                __half* __restrict__ xlh,
                                                float* __restrict__ xr,
                                                const int* __restrict__ flagp)
{
    __shared__ __align__(16) char lds[64 * ELX_S * 2 + 64 * EXR_S * 4]; // 26624 B
    _Float16* xs  = (_Float16*)lds;                    // stage: 64*F fp16 (<=16KB)
    _Float16* eXL = (_Float16*)lds;                    // epilogue xl 64x72 fp16
    float*    eXR = (float*)(lds + 64 * ELX_S * 2);    // epilogue xr 64x68 fp32

    const int tid = threadIdx.x;
    const int nb = blockIdx.x * 64;
    constexpr int OPR = F / 8;     // octets per row

    // ---- stage h -> swizzled fp16 LDS ----
    if (L0 && flagp[0]) {
        const uint4* hp = (const uint4*)hin_;
        for (int c = tid; c < 64 * OPR; c += 256) {
            int row = c / OPR, oct = c % OPR;
            uint4 u = hp[((size_t)(nb + row) * F + oct * 8) >> 3];
            unsigned ww[4] = { u.x, u.y, u.z, u.w };
            _Float16 v[8];
            #pragma unroll
            for (int p = 0; p < 4; p++) {
                v[2 * p]     = (_Float16)__uint_as_float(ww[p] << 16);
                v[2 * p + 1] = (_Float16)__uint_as_float(ww[p] & 0xffff0000u);
            }
            int so = oct ^ (row & 7);
            *(f16x8*)&xs[row * F + so * 8] = *(f16x8*)v;
        }
    } else {
        const float4* hp = (const float4*)hin_;
        for (int c = tid; c < 64 * OPR; c += 256) {
            int row = c / OPR, oct = c % OPR;
            size_t base = ((size_t)(nb + row) * F + oct * 8) >> 2;
            float4 a = hp[base], b = hp[base + 1];
            _Float16 v[8] = { (_Float16)a.x, (_Float16)a.y, (_Float16)a.z, (_Float16)a.w,
                              (_Float16)b.x, (_Float16)b.y, (_Float16)b.z, (_Float16)b.w };
            int so = oct ^ (row & 7);
            *(f16x8*)&xs[row * F + so * 8] = *(f16x8*)v;
        }
    }
    __syncthreads();

    const int w = tid >> 6;
    const int lane = tid & 63;
    const int n = lane & 15;
    const int quad = lane >> 4;
    constexpr int NS = F / 32;

    f16x8 afr[NS];
    #pragma unroll
    for (int s = 0; s < NS; s++) {
        int o = (s * 4 + quad) ^ (n & 7);
        afr[s] = *(const f16x8*)&xs[(w * 16 + n) * F + o * 8];
    }
    __syncthreads();   // xs dead; LDS reused for epilogue

    const _Float16* Whf = (const _Float16*)Wh;
    #pragma unroll
    for (int ct = 0; ct < 8; ct++) {
        float bv = biasLR[ct * 16 + n];
        f32x4 acc = { bv, bv, bv, bv };
        #pragma unroll
        for (int s = 0; s < NS; s++) {
            f16x8 bfr = *(const f16x8*)&Whf[(size_t)(ct * 16 + n) * F + s * 32 + quad * 8];
            acc = __builtin_amdgcn_mfma_f32_16x16x32_f16(afr[s], bfr, acc, 0, 0, 0);
        }
        int rbase = w * 16 + quad * 4;
        if (ct < 4) {
            #pragma unroll
            for (int rg = 0; rg < 4; rg++)
                eXL[(rbase + rg) * ELX_S + ct * 16 + n] = (_Float16)acc[rg];
        } else {
            #pragma unroll
            for (int rg = 0; rg < 4; rg++)
                eXR[(rbase + rg) * EXR_S + (ct - 4) * 16 + n] = acc[rg];
        }
    }
    __syncthreads();

    // ---- vectorized writeout ----
    for (int c = tid; c < 512; c += 256) {          // xl: 64 rows x 64 fp16
        int row = c >> 3, oct = c & 7;
        *(uint4*)&xlh[(size_t)(nb + row) * 64 + oct * 8] =
            *(const uint4*)&eXL[row * ELX_S + oct * 8];
    }
    for (int c = tid; c < 1024; c += 256) {         // xr: 64 rows x 64 fp32
        int row = c >> 4, q4 = c & 15;
        *(float4*)&xr[(size_t)(nb + row) * 64 + q4 * 4] =
            *(const float4*)&eXR[row * EXR_S + q4 * 4];
    }
}

// ---------------- fused score+aggregate: wave/node, 8 rows per gather -------
#define DECODE8(U, D) { \
    float2 _f0 = __half22float2(*(__half2*)&U.x); \
    float2 _f1 = __half22float2(*(__half2*)&U.y); \
    float2 _f2 = __half22float2(*(__half2*)&U.z); \
    float2 _f3 = __half22float2(*(__half2*)&U.w); \
    D[0]=_f0.x; D[1]=_f0.y; D[2]=_f1.x; D[3]=_f1.y; \
    D[4]=_f2.x; D[5]=_f2.y; D[6]=_f3.x; D[7]=_f3.y; }

__global__ __launch_bounds__(256) void agg4_kernel(const __half* __restrict__ xlh,
                                                   const float* __restrict__ xr,
                                                   const float* __restrict__ attf,
                                                   const float* __restrict__ bf,
                                                   const int* __restrict__ rowptr,
                                                   const int2* __restrict__ col2,
                                                   float* __restrict__ hout)
{
    const int lane = threadIdx.x & 63;
    const int g = lane >> 3;        // subgroup -> edge slot
    const int r = lane & 7;         // feature octet
    int iw = blockIdx.x * 4 + (threadIdx.x >> 6);
    if (iw >= NN) return;
    const int i = __builtin_amdgcn_readfirstlane(iw);

    float xri[8], att[8];
    {
        float4 xa = *(const float4*)(xr + (size_t)i * 64 + r * 8);
        float4 xb = *(const float4*)(xr + (size_t)i * 64 + r * 8 + 4);
        xri[0]=xa.x; xri[1]=xa.y; xri[2]=xa.z; xri[3]=xa.w;
        xri[4]=xb.x; xri[5]=xb.y; xri[6]=xb.z; xri[7]=xb.w;
        float4 aa = *(const float4*)(attf + r * 8);
        float4 ab = *(const float4*)(attf + r * 8 + 4);
        att[0]=aa.x; att[1]=aa.y; att[2]=aa.z; att[3]=aa.w;
        att[4]=ab.x; att[5]=ab.y; att[6]=ab.z; att[7]=ab.w;
    }

    uint4 srow = *(const uint4*)(xlh + (size_t)i * 64 + r * 8);
    float s[8]; DECODE8(srow, s);
    float ps = 0.f;
    #pragma unroll
    for (int k = 0; k < 8; k++) {
        float u = s[k] + xri[k];
        ps = fmaf(att[k], fmaf(0.4f, fabsf(u), 0.6f * u), ps);
    }
    ps += __shfl_xor(ps, 1, 64);
    ps += __shfl_xor(ps, 2, 64);
    ps += __shfl_xor(ps, 4, 64);
    float wself = __expf(fminf(ps, 60.f));

    float acc[8];
    float denom;
    if (g == 0) {
        #pragma unroll
        for (int k = 0; k < 8; k++) acc[k] = wself * s[k];
        denom = wself;
    } else {
        #pragma unroll
        for (int k = 0; k < 8; k++) acc[k] = 0.f;
        denom = 0.f;
    }

    const int e0 = rowptr[i], e1 = rowptr[i + 1];
    const int n = e1 - e0;
    const int eL = e1 - 1;

    for (int base = 0; base < n; base += 16) {
        const int j = e0 + base;
        int sa = col2[min(j + g, eL)].x;
        int sb = col2[min(j + 8 + g, eL)].x;
        uint4 ua = *(const uint4*)(xlh + (size_t)sa * 64 + r * 8);
        uint4 ub = *(const uint4*)(xlh + (size_t)sb * 64 + r * 8);
        float A[8], B[8];
        DECODE8(ua, A);
        DECODE8(ub, B);

        float pa = 0.f, pb = 0.f;
        #pragma unroll
        for (int k = 0; k < 8; k++) {
            float va = A[k] + xri[k];
            float vb = B[k] + xri[k];
            pa = fmaf(att[k], fmaf(0.4f, fabsf(va), 0.6f * va), pa);
            pb = fmaf(att[k], fmaf(0.4f, fabsf(vb), 0.6f * vb), pb);
        }
        pa += __shfl_xor(pa, 1, 64);  pb += __shfl_xor(pb, 1, 64);
        pa += __shfl_xor(pa, 2, 64);  pb += __shfl_xor(pb, 2, 64);
        pa += __shfl_xor(pa, 4, 64);  pb += __shfl_xor(pb, 4, 64);

        float wa = (base + g < n)     ? __expf(fminf(pa, 60.f)) : 0.f;
        float wb = (base + 8 + g < n) ? __expf(fminf(pb, 60.f)) : 0.f;

        #pragma unroll
        for (int k = 0; k < 8; k++) {
            acc[k] = fmaf(wa, A[k], acc[k]);
            acc[k] = fmaf(wb, B[k], acc[k]);
        }
        denom += wa + wb;
    }

    #pragma unroll
    for (int off = 8; off < 64; off <<= 1) {
        #pragma unroll
        for (int k = 0; k < 8; k++) acc[k] += __shfl_xor(acc[k], off, 64);
        denom += __shfl_xor(denom, off, 64);
    }

    if (g == 0) {
        float inv = 1.f / denom;
        float4 bfa = *(const float4*)(bf + r * 8);
        float4 bfb = *(const float4*)(bf + r * 8 + 4);
        float o0 = fmaxf(fmaf(acc[0], inv, bfa.x), 0.f);
        float o1 = fmaxf(fmaf(acc[1], inv, bfa.y), 0.f);
        float o2 = fmaxf(fmaf(acc[2], inv, bfa.z), 0.f);
        float o3 = fmaxf(fmaf(acc[3], inv, bfa.w), 0.f);
        float o4 = fmaxf(fmaf(acc[4], inv, bfb.x), 0.f);
        float o5 = fmaxf(fmaf(acc[5], inv, bfb.y), 0.f);
        float o6 = fmaxf(fmaf(acc[6], inv, bfb.z), 0.f);
        float o7 = fmaxf(fmaf(acc[7], inv, bfb.w), 0.f);
        float* op = hout + (size_t)i * 64 + r * 8;
        *(float4*)(op)     = make_float4(o0, o1, o2, o3);
        *(float4*)(op + 4) = make_float4(o4, o5, o6, o7);
    }
}

// ---------------- readout: thread-per-node serial dot, Wro^T in LDS --------
__global__ __launch_bounds__(256) void readout2_kernel(const float* __restrict__ h,
                                                       const float* __restrict__ WROf,
                                                       const float* __restrict__ brof,
                                                       void* __restrict__ out,
                                                       const int* __restrict__ flagp)
{
    __shared__ float wsh[640];   // wsh[k*10+o] = Wro[o][k]
    __shared__ float bsh[OUTD];
    const int tid = threadIdx.x;
    for (int idx = tid; idx < 640; idx += 256) {
        int k = idx / 10, o = idx % 10;
        wsh[idx] = WROf[o * 64 + k];
    }
    if (tid < OUTD) bsh[tid] = brof[tid];
    __syncthreads();

    const int i = blockIdx.x * 256 + tid;
    if (i >= NN) return;
    const int f = flagp[0];

    float res[OUTD];
    #pragma unroll
    for (int o = 0; o < OUTD; o++) res[o] = bsh[o];

    const float4* h4 = (const float4*)(h + (size_t)i * 64);
    #pragma unroll 4
    for (int c = 0; c < 16; c++) {
        float4 hv = h4[c];
        const float* wp = &wsh[c * 40];
        #pragma unroll
        for (int o = 0; o < OUTD; o++) {
            float t = fmaf(hv.x, wp[o], fmaf(hv.y, wp[10 + o],
                      fmaf(hv.z, wp[20 + o], hv.w * wp[30 + o])));
            res[o] += t;
        }
    }

    if (f) {
        bf16* op = (bf16*)out + (size_t)i * OUTD;
        #pragma unroll
        for (int o = 0; o < OUTD; o++) op[o] = __float2bfloat16(res[o]);
    } else {
        float* op = (float*)out + (size_t)i * OUTD;
        #pragma unroll
        for (int o = 0; o < OUTD; o++) op[o] = res[o];
    }
}

extern "C" void kernel_launch(void* const* d_in, const int* in_sizes, int n_in,
                              void* d_out, int out_size, void* d_ws, size_t ws_size,
                              hipStream_t stream) {
    const void* x   = d_in[0];
    const int* ei   = (const int*)d_in[1];
    const void* Wl0 = d_in[3];  const void* bl0 = d_in[4];
    const void* Wr0 = d_in[5];  const void* br0 = d_in[6];
    const void* at0 = d_in[7];  const void* b0  = d_in[8];
    const void* Wl1 = d_in[9];  const void* bl1 = d_in[10];
    const void* Wr1 = d_in[11]; const void* br1 = d_in[12];
    const void* at1 = d_in[13]; const void* b1  = d_in[14];
    const void* Wl2 = d_in[15]; const void* bl2 = d_in[16];
    const void* Wr2 = d_in[17]; const void* br2 = d_in[18];
    const void* at2 = d_in[19]; const void* b2  = d_in[20];
    const void* Wro = d_in[21]; const void* bro = d_in[22];

    const int* srcArr = ei;
    const int* dstArr = ei + EE;

    float* wf = (float*)d_ws;
    __half* Wh0  = (__half*)wf;               // 16384 halves (slot 16384 floats)
    __half* Wh1  = (__half*)(wf + 16384);     // 8192 halves
    __half* Wh2  = (__half*)(wf + 24576);     // 8192 halves
    float* small = wf + 32768;                // 1536
    int*   flag  = (int*)(wf + 34304);        // pad 64
    int*   rowptr = (int*)(wf + 34368);       // 80001 (pad 80128)
    int*   bsums  = (int*)(wf + 114496);      // 512
    int*   fillc  = (int*)(wf + 115008);      // 80000 (per-dst counts)
    int*   bucket_cnt  = (int*)(wf + 195008); // 128
    int*   bucket_base = (int*)(wf + 195136); // 128 (+1 used)
    int*   chunkcnt    = (int*)(wf + 195264); // NBUK*NCH = 49375 (pad 49472)
    int2*  part   = (int2*)(wf + 244736);     // EE int2 = 2560000 ints
    int2*  col2   = (int2*)(wf + 2804736);    // 2560000
    __half* xlh   = (__half*)(wf + 5364736);  // NN*64 halves = 2560000 floats
    float* xr = wf + 7924736;                 // 5120000
    float* hA = xr + (size_t)NN * 64;         // 5120000

    float* biasLR0 = small;        float* biasLR1 = small + 128; float* biasLR2 = small + 256;
    float* attf0 = small + 384;    float* attf1 = small + 448;   float* attf2 = small + 512;
    float* bf0   = small + 576;    float* bf1   = small + 640;   float* bf2   = small + 704;
    float* WROf  = small + 768;    float* brof  = small + 1408;

    detect_kernel<<<dim3(1), dim3(64), 0, stream>>>((const unsigned*)Wl0, flag);

    preconvert<<<dim3(134), dim3(256), 0, stream>>>(
        Wl0, Wr0, Wl1, Wr1, Wl2, Wr2, bl0, br0, bl1, br1, bl2, br2,
        at0, at1, at2, b0, b1, b2, Wro, bro, Wh0, Wh1, Wh2, small, flag);

    // deterministic edge sort
    chunkhist_kernel<<<dim3(NCH), dim3(256), 0, stream>>>(dstArr, chunkcnt);
    cscan_kernel<<<dim3(NBUK), dim3(1024), 0, stream>>>(chunkcnt, bucket_cnt);
    bscan_kernel<<<dim3(1), dim3(128), 0, stream>>>(bucket_cnt, bucket_base);
    part_kernel<<<dim3(NCH), dim3(256), 0, stream>>>(srcArr, dstArr, chunkcnt, bucket_base, part);
    hist_part_kernel<<<dim3(NBUK), dim3(256), 0, stream>>>(part, bucket_base, fillc);
    scan1<<<dim3(313), dim3(256), 0, stream>>>(fillc, rowptr, bsums);
    scan2<<<dim3(1), dim3(512), 0, stream>>>(bsums, 313);
    scan3<<<dim3(313), dim3(256), 0, stream>>>(rowptr, bsums);
    scatter2_kernel<<<dim3(NBUK), dim3(256), 0, stream>>>(part, bucket_base, rowptr, col2);

    // layer 0
    lin_mfma<128, true><<<dim3(NN / 64), dim3(256), 0, stream>>>(x, Wh0, biasLR0, xlh, xr, flag);
    agg4_kernel<<<dim3(NN / 4), dim3(256), 0, stream>>>(xlh, xr, attf0, bf0, rowptr, col2, hA);
    // layer 1
    lin_mfma<64, false><<<dim3(NN / 64), dim3(256), 0, stream>>>(hA, Wh1, biasLR1, xlh, xr, flag);
    agg4_kernel<<<dim3(NN / 4), dim3(256), 0, stream>>>(xlh, xr, attf1, bf1, rowptr, col2, hA);
    // layer 2
    lin_mfma<64, false><<<dim3(NN / 64), dim3(256), 0, stream>>>(hA, Wh2, biasLR2, xlh, xr, flag);
    agg4_kernel<<<dim3(NN / 4), dim3(256), 0, stream>>>(xlh, xr, attf2, bf2, rowptr, col2, hA);

    // readout (thread-per-node serial dot)
    readout2_kernel<<<dim3(313), dim3(256), 0, stream>>>(hA, WROf, brof, d_out, flag);
}